// Round 10
// baseline (165.808 us; speedup 1.0000x reference)
//
#include <hip/hip_runtime.h>
#include <hip/hip_bf16.h>

#define CC 128
#define NSP 16384              // 128*128 spatial
#define NFULL (CC * NSP)

typedef float f32x4 __attribute__((ext_vector_type(4)));
typedef short s16x8 __attribute__((ext_vector_type(8)));
typedef unsigned int u32x4 __attribute__((ext_vector_type(4)));

__device__ __forceinline__ unsigned bf16rne(float f) {
  unsigned u = __float_as_uint(f);
  return ((u + 0x7FFFu + ((u >> 16) & 1u)) >> 16) & 0xFFFFu;
}

// RNE hi/lo split of a float pair -> packed {hi, lo} u32 (bf16x2 each)
__device__ __forceinline__ uint2 packpair(float x0, float x1) {
  __hip_bfloat162 h2 = __float22bfloat162_rn(make_float2(x0, x1));
  unsigned hu = *reinterpret_cast<unsigned*>(&h2);   // lo16=bf16(x0), hi16=bf16(x1)
  float hf0 = __uint_as_float(hu << 16);
  float hf1 = __uint_as_float(hu & 0xFFFF0000u);
  __hip_bfloat162 l2 = __float22bfloat162_rn(make_float2(x0 - hf0, x1 - hf1));
  unsigned lu = *reinterpret_cast<unsigned*>(&l2);
  return make_uint2(hu, lu);
}

// zero M/rs/rt (mode-1 fallback only)
__global__ __launch_bounds__(256) void zerok(float* __restrict__ p, int n) {
  int i = blockIdx.x * 256 + threadIdx.x;
  if (i < n) p[i] = 0.f;
}

// ---------------------------------------------------------------------------
// K1 (MFMA, LDS-staged, 4 waves — best measured config R8): per (chunk,b):
// partial Xt*Xs^T over 64-n stages, convert-once hi/lo bf16 staging in
// XOR-swizzled LDS. Partials written with NT stores (don't evict x from L3).
// ---------------------------------------------------------------------------
__global__ __launch_bounds__(256, 2) void k1_mfma(const float* __restrict__ x,
    float* __restrict__ Mdst, float* __restrict__ rs, float* __restrict__ rt,
    float* __restrict__ rspart, float* __restrict__ rtpart,
    int nst, int mode) {
  const int b = blockIdx.y;
  const int chunk = blockIdx.x;
  const int n0 = chunk * (nst * 64);
  const int t = threadIdx.x;
  const int w = t >> 6, l = t & 63;
  const int wr = w >> 1, wc = w & 1;
  const int lr = l & 15, lg = l >> 4;
  const int r0 = t >> 2;               // staging row 0..63 (and +64)
  const int q = t & 3;                 // staging n-quarter (16 floats)
  __shared__ unsigned short Ahi[128 * 64];   // 16KB each, swz: byte^((row&7)<<4)
  __shared__ unsigned short Alo[128 * 64];
  __shared__ unsigned short Bhi[128 * 64];
  __shared__ unsigned short Blo[128 * 64];
  const float* Xs = x + (size_t)b * NFULL;
  const float* Xt = x + (size_t)(b + 8) * NFULL;

  f32x4 acc[4][4];
#pragma unroll
  for (int a = 0; a < 4; ++a)
#pragma unroll
    for (int bb = 0; bb < 4; ++bb) acc[a][bb] = (f32x4){0.f, 0.f, 0.f, 0.f};
  float rtp[2] = {0.f, 0.f}, rsp[2] = {0.f, 0.f};

  for (int s = 0; s < nst; ++s) {
    const int nb = n0 + s * 64;
    __syncthreads();                   // prev-stage reads done before overwrite
#pragma unroll
    for (int p = 0; p < 2; ++p) {
      const int row = r0 + 64 * p;
      const float* At = Xt + (size_t)row * NSP + nb + q * 16;
      const float* Bs = Xs + (size_t)row * NSP + nb + q * 16;
      f32x4 av[4], bv[4];
#pragma unroll
      for (int i = 0; i < 4; ++i) av[i] = *(const f32x4*)(At + i * 4);
#pragma unroll
      for (int i = 0; i < 4; ++i) bv[i] = *(const f32x4*)(Bs + i * 4);
#pragma unroll
      for (int i = 0; i < 4; ++i) {
        rtp[p] += (av[i][0] + av[i][1]) + (av[i][2] + av[i][3]);
        rsp[p] += (bv[i][0] + bv[i][1]) + (bv[i][2] + bv[i][3]);
      }
      u32x4 h0, l0, h1, l1;
#pragma unroll
      for (int i = 0; i < 2; ++i) {
        uint2 r1 = packpair(av[i][0], av[i][1]);
        h0[2 * i] = r1.x; l0[2 * i] = r1.y;
        uint2 r2 = packpair(av[i][2], av[i][3]);
        h0[2 * i + 1] = r2.x; l0[2 * i + 1] = r2.y;
        uint2 r3 = packpair(av[2 + i][0], av[2 + i][1]);
        h1[2 * i] = r3.x; l1[2 * i] = r3.y;
        uint2 r4 = packpair(av[2 + i][2], av[2 + i][3]);
        h1[2 * i + 1] = r4.x; l1[2 * i + 1] = r4.y;
      }
      {
        int base = row * 128 + q * 32;
        int sw = (row & 7) << 4;
        *(u32x4*)((char*)Ahi + ((base) ^ sw)) = h0;
        *(u32x4*)((char*)Ahi + ((base + 16) ^ sw)) = h1;
        *(u32x4*)((char*)Alo + ((base) ^ sw)) = l0;
        *(u32x4*)((char*)Alo + ((base + 16) ^ sw)) = l1;
      }
#pragma unroll
      for (int i = 0; i < 2; ++i) {
        uint2 r1 = packpair(bv[i][0], bv[i][1]);
        h0[2 * i] = r1.x; l0[2 * i] = r1.y;
        uint2 r2 = packpair(bv[i][2], bv[i][3]);
        h0[2 * i + 1] = r2.x; l0[2 * i + 1] = r2.y;
        uint2 r3 = packpair(bv[2 + i][0], bv[2 + i][1]);
        h1[2 * i] = r3.x; l1[2 * i] = r3.y;
        uint2 r4 = packpair(bv[2 + i][2], bv[2 + i][3]);
        h1[2 * i + 1] = r4.x; l1[2 * i + 1] = r4.y;
      }
      {
        int base = row * 128 + q * 32;
        int sw = (row & 7) << 4;
        *(u32x4*)((char*)Bhi + ((base) ^ sw)) = h0;
        *(u32x4*)((char*)Bhi + ((base + 16) ^ sw)) = h1;
        *(u32x4*)((char*)Blo + ((base) ^ sw)) = l0;
        *(u32x4*)((char*)Blo + ((base + 16) ^ sw)) = l1;
      }
    }
    __syncthreads();
#pragma unroll
    for (int kk = 0; kk < 2; ++kk) {
      s16x8 ah[4], al[4], bh[4], bl[4];
#pragma unroll
      for (int a = 0; a < 4; ++a) {
        int row = wr * 64 + a * 16 + lr;
        int off = (row * 128 + kk * 64 + lg * 16) ^ ((row & 7) << 4);
        ah[a] = *(const s16x8*)((char*)Ahi + off);
        al[a] = *(const s16x8*)((char*)Alo + off);
      }
#pragma unroll
      for (int bb = 0; bb < 4; ++bb) {
        int row = wc * 64 + bb * 16 + lr;
        int off = (row * 128 + kk * 64 + lg * 16) ^ ((row & 7) << 4);
        bh[bb] = *(const s16x8*)((char*)Bhi + off);
        bl[bb] = *(const s16x8*)((char*)Blo + off);
      }
#pragma unroll
      for (int a = 0; a < 4; ++a)
#pragma unroll
        for (int bb = 0; bb < 4; ++bb) {
          acc[a][bb] = __builtin_amdgcn_mfma_f32_16x16x32_bf16(ah[a], bh[bb], acc[a][bb], 0, 0, 0);
          acc[a][bb] = __builtin_amdgcn_mfma_f32_16x16x32_bf16(ah[a], bl[bb], acc[a][bb], 0, 0, 0);
          acc[a][bb] = __builtin_amdgcn_mfma_f32_16x16x32_bf16(al[a], bh[bb], acc[a][bb], 0, 0, 0);
        }
    }
  }

  // row-sum reduce over the 4 n-quarters (q = lane&3)
#pragma unroll
  for (int p = 0; p < 2; ++p) {
    float vt = rtp[p];
    vt += __shfl_xor(vt, 1);
    vt += __shfl_xor(vt, 2);
    float vs = rsp[p];
    vs += __shfl_xor(vs, 1);
    vs += __shfl_xor(vs, 2);
    if (q == 0) {
      int row = r0 + 64 * p;
      if (mode == 0) {
        __builtin_nontemporal_store(vt, &rtpart[((size_t)chunk * 8 + b) * CC + row]);
        __builtin_nontemporal_store(vs, &rspart[((size_t)chunk * 8 + b) * CC + row]);
      } else {
        atomicAdd(&rt[b * CC + row], vt);
        atomicAdd(&rs[b * CC + row], vs);
      }
    }
  }

  const int rquad = lg << 2;
  if (mode == 0) {
    float* Mp = Mdst + ((size_t)chunk * 8 + b) * (CC * CC);
#pragma unroll
    for (int a = 0; a < 4; ++a)
#pragma unroll
      for (int bb = 0; bb < 4; ++bb)
#pragma unroll
        for (int r = 0; r < 4; ++r) {
          int i = wr * 64 + a * 16 + rquad + r;
          int j = wc * 64 + bb * 16 + lr;
          __builtin_nontemporal_store(acc[a][bb][r], &Mp[i * CC + j]);
        }
  } else {
    float* Mp = Mdst + (size_t)b * (CC * CC);
#pragma unroll
    for (int a = 0; a < 4; ++a)
#pragma unroll
      for (int bb = 0; bb < 4; ++bb)
#pragma unroll
        for (int r = 0; r < 4; ++r) {
          int i = wr * 64 + a * 16 + rquad + r;
          int j = wc * 64 + bb * 16 + lr;
          atomicAdd(&Mp[i * CC + j], acc[a][bb][r]);
        }
  }
}

// Sum partials, vectorized + NT loads (partials are read-once; keep x in L3).
// Blocks [0,128): M. Block 128: rt. Block 129: rs.
__global__ __launch_bounds__(256) void k1_reduce(const float* __restrict__ Mpart,
    const float* __restrict__ rspart, const float* __restrict__ rtpart,
    float* __restrict__ M, float* __restrict__ rs, float* __restrict__ rt,
    int NB) {
  const int t = threadIdx.x;
  if (blockIdx.x < 128) {
    const int i4 = blockIdx.x * 256 + t;     // < 32768
    const int b = i4 >> 12;
    const int e = (i4 & 4095) * 4;
    f32x4 s = (f32x4){0.f, 0.f, 0.f, 0.f};
    for (int c = 0; c < NB; ++c) {
      f32x4 v = __builtin_nontemporal_load(
          (const f32x4*)(Mpart + ((size_t)c * 8 + b) * (CC * CC) + e));
      s += v;
    }
    *(f32x4*)(M + (size_t)b * CC * CC + e) = s;
  } else if (blockIdx.x == 128) {
    const int e = t * 4;                      // < 1024
    f32x4 s = (f32x4){0.f, 0.f, 0.f, 0.f};
    for (int c = 0; c < NB; ++c)
      s += __builtin_nontemporal_load((const f32x4*)(rtpart + (size_t)c * 1024 + e));
    *(f32x4*)(rt + e) = s;
  } else {
    const int e = t * 4;
    f32x4 s = (f32x4){0.f, 0.f, 0.f, 0.f};
    for (int c = 0; c < NB; ++c)
      s += __builtin_nontemporal_load((const f32x4*)(rspart + (size_t)c * 1024 + e));
    *(f32x4*)(rs + e) = s;
  }
}

// ---------------------------------------------------------------------------
// K2ab fused: T1=Wq*M, T2=Wq*M^T, us/ut, G + softmax (st & ts).
// grid (16 c-groups of 8 rows, 8 b). Cols strided: lane L owns {L+32j}.
// ---------------------------------------------------------------------------
__global__ __launch_bounds__(256) void k2ab(const float* __restrict__ M,
    const float* __restrict__ qw, const float* __restrict__ kw,
    const float* __restrict__ qb, const float* __restrict__ kb,
    const float* __restrict__ rs, const float* __restrict__ rt,
    float* __restrict__ Ast, float* __restrict__ Ats) {
  const int b = blockIdx.y;
  const int c0 = blockIdx.x * 8;
  __shared__ float Big[128][132];      // M, later Wk (132: 16B-aligned rows)
  __shared__ float Wq[8][128];
  __shared__ float T12[2][8][128];
  __shared__ float uvv[2][8];
  __shared__ float wv2[2][128];
  const int t = threadIdx.x;
  const float* Mb = M + (size_t)b * CC * CC;
#pragma unroll
  for (int p = 0; p < 16; ++p) {
    int f = p * 256 + t;
    int row = f >> 5, c4 = (f & 31) * 4;
    *(f32x4*)&Big[row][c4] = *(const f32x4*)(Mb + row * CC + c4);
  }
  { int row = t >> 5, c4 = (t & 31) * 4;
    *(f32x4*)&Wq[row][c4] = *(const f32x4*)(qw + (c0 + row) * CC + c4); }
  __syncthreads();
  if (t < 16) {
    int c = t & 7;
    const float* r = ((t < 8) ? rs : rt) + b * CC;
    float s = 0.f;
    for (int i = 0; i < CC; ++i) s += Wq[c][i] * r[i];
    uvv[(t < 8) ? 1 : 0][c] = s;       // us->[1], ut->[0]
  }
  const int tr = t >> 5;               // row 0..7
  const int L = t & 31;                // col lane
  {
    float a1[4] = {0.f, 0.f, 0.f, 0.f}, a2[4] = {0.f, 0.f, 0.f, 0.f};
    for (int i = 0; i < CC; ++i) {
      float wq = Wq[tr][i];
#pragma unroll
      for (int j = 0; j < 4; ++j) a1[j] += wq * Big[i][L + 32 * j];
    }
    for (int i4 = 0; i4 < 32; ++i4) {
      f32x4 wq4 = *(const f32x4*)&Wq[tr][i4 * 4];
#pragma unroll
      for (int j = 0; j < 4; ++j) {
        f32x4 m4 = *(const f32x4*)&Big[L + 32 * j][i4 * 4];
        a2[j] += wq4[0]*m4[0] + wq4[1]*m4[1] + wq4[2]*m4[2] + wq4[3]*m4[3];
      }
    }
#pragma unroll
    for (int j = 0; j < 4; ++j) {
      T12[0][tr][L + 32 * j] = a1[j];
      T12[1][tr][L + 32 * j] = a2[j];
    }
  }
  __syncthreads();
  // overwrite Big with Wk
#pragma unroll
  for (int p = 0; p < 16; ++p) {
    int f = p * 256 + t;
    int row = f >> 5, c4 = (f & 31) * 4;
    *(f32x4*)&Big[row][c4] = *(const f32x4*)(kw + row * CC + c4);
  }
  __syncthreads();
  {
    int d = t & 127, wh = t >> 7;      // 0: rs, 1: rt
    const float* r = (wh ? rt : rs) + b * CC;
    float s = 0.f;
    for (int i4 = 0; i4 < 32; ++i4) {
      f32x4 w4 = *(const f32x4*)&Big[d][i4 * 4];
      s += w4[0]*r[i4*4] + w4[1]*r[i4*4+1] + w4[2]*r[i4*4+2] + w4[3]*r[i4*4+3];
    }
    wv2[wh][d] = s;
  }
  __syncthreads();
  const int c = c0 + tr;
  const float bqc = qb[c];
#pragma unroll 1
  for (int which = 0; which < 2; ++which) {
    float g[4];
#pragma unroll
    for (int j = 0; j < 4; ++j) {
      int d = L + 32 * j;
      g[j] = uvv[which][tr] * kb[d] + bqc * wv2[which][d] + 16384.f * bqc * kb[d];
    }
    for (int j4 = 0; j4 < 32; ++j4) {
      f32x4 tv4 = *(const f32x4*)&T12[which][tr][j4 * 4];
#pragma unroll
      for (int j = 0; j < 4; ++j) {
        f32x4 w4 = *(const f32x4*)&Big[L + 32 * j][j4 * 4];
        g[j] += tv4[0]*w4[0] + tv4[1]*w4[1] + tv4[2]*w4[2] + tv4[3]*w4[3];
      }
    }
    float m = fmaxf(fmaxf(g[0], g[1]), fmaxf(g[2], g[3]));
#pragma unroll
    for (int off = 1; off < 32; off <<= 1) m = fmaxf(m, __shfl_xor(m, off));
    float s = 0.f;
#pragma unroll
    for (int j = 0; j < 4; ++j) { g[j] = expf(g[j] - m); s += g[j]; }
#pragma unroll
    for (int off = 1; off < 32; off <<= 1) s += __shfl_xor(s, off);
    const float inv = 1.f / s;
    float* A = (which ? Ats : Ast) + (size_t)b * CC * CC + (size_t)c * CC;
#pragma unroll
    for (int j = 0; j < 4; ++j) A[L + 32 * j] = g[j] * inv;
  }
}

// ---------------------------------------------------------------------------
// K2cd fused: L = Ast*Ats^T, softmax -> Att, P' = Att*Wv + I (bf16), c0.
// grid (16 c-groups of 8 rows, 8 b).
// ---------------------------------------------------------------------------
__global__ __launch_bounds__(256) void k2cd(const float* __restrict__ Ast,
    const float* __restrict__ Ats, const float* __restrict__ vw,
    const float* __restrict__ vb, unsigned short* __restrict__ Pbf,
    float* __restrict__ c0v) {
  const int b = blockIdx.y;
  const int c0 = blockIdx.x * 8;
  __shared__ float Big[128][132];      // Ats, later Wv[d][i]
  __shared__ float Tl[8][128];
  __shared__ float Al[8][128];
  const int t = threadIdx.x;
  const float* Bb = Ats + (size_t)b * CC * CC;
  const float* Tb = Ast + (size_t)b * CC * CC;
#pragma unroll
  for (int p = 0; p < 16; ++p) {
    int f = p * 256 + t;
    int row = f >> 5, c4 = (f & 31) * 4;
    *(f32x4*)&Big[row][c4] = *(const f32x4*)(Bb + row * CC + c4);
  }
  { int row = t >> 5, c4 = (t & 31) * 4;
    *(f32x4*)&Tl[row][c4] = *(const f32x4*)(Tb + (c0 + row) * CC + c4); }
  __syncthreads();
  const int tr = t >> 5;
  const int L = t & 31;
  {
    float g[4] = {0.f, 0.f, 0.f, 0.f};
    for (int e4 = 0; e4 < 32; ++e4) {
      f32x4 tv4 = *(const f32x4*)&Tl[tr][e4 * 4];
#pragma unroll
      for (int j = 0; j < 4; ++j) {
        f32x4 a4 = *(const f32x4*)&Big[L + 32 * j][e4 * 4];
        g[j] += tv4[0]*a4[0] + tv4[1]*a4[1] + tv4[2]*a4[2] + tv4[3]*a4[3];
      }
    }
    float m = fmaxf(fmaxf(g[0], g[1]), fmaxf(g[2], g[3]));
#pragma unroll
    for (int off = 1; off < 32; off <<= 1) m = fmaxf(m, __shfl_xor(m, off));
    float s = 0.f;
#pragma unroll
    for (int j = 0; j < 4; ++j) { g[j] = expf(g[j] - m); s += g[j]; }
#pragma unroll
    for (int off = 1; off < 32; off <<= 1) s += __shfl_xor(s, off);
    const float inv = 1.f / s;
#pragma unroll
    for (int j = 0; j < 4; ++j) Al[tr][L + 32 * j] = g[j] * inv;
  }
  __syncthreads();
  // overwrite Big with Wv[d][i]
#pragma unroll
  for (int p = 0; p < 16; ++p) {
    int f = p * 256 + t;
    int row = f >> 5, c4 = (f & 31) * 4;
    *(f32x4*)&Big[row][c4] = *(const f32x4*)(vw + row * CC + c4);
  }
  __syncthreads();
  float p4[4] = {0.f, 0.f, 0.f, 0.f};
  for (int d = 0; d < CC; ++d) {
    float av = Al[tr][d];
#pragma unroll
    for (int j = 0; j < 4; ++j) p4[j] += av * Big[d][L + 32 * j];
  }
  float csum = 0.f;
#pragma unroll
  for (int j = 0; j < 4; ++j) csum += Al[tr][L + 32 * j] * vb[L + 32 * j];
#pragma unroll
  for (int off = 1; off < 32; off <<= 1) csum += __shfl_xor(csum, off);
  const int c = c0 + tr;
  if ((c & 31) == L) p4[c >> 5] += 1.0f;      // P' = P + I (residual folded in)
  unsigned short* Pp = Pbf + (size_t)b * CC * CC + (size_t)c * CC;
#pragma unroll
  for (int j = 0; j < 4; ++j) Pp[L + 32 * j] = (unsigned short)bf16rne(p4[j]);
  if (L == 0) c0v[b * CC + c] = csum;
}

// ---------------------------------------------------------------------------
// K3 (MFMA): out[c][n] = sum_e P'[c][e]*x[e][n] + c0[c]  (identity in P').
// 128-n tile per block (LDS 32.5KB -> 3 blocks/CU, 12 waves/CU); staged
// transposed bf16 (swizzled); P' frags hoisted per c-half, reused over 2
// subtiles. NT output stores. grid (128 n-tiles, 16 images), 4 waves.
// ---------------------------------------------------------------------------
__global__ __launch_bounds__(256, 3) void k3_mfma(const float* __restrict__ x,
    const unsigned short* __restrict__ Pbf, const float* __restrict__ c0v,
    float* __restrict__ out) {
  const int im = blockIdx.y;
  const int pb = im & 7;
  const int n0 = blockIdx.x * 128;
  const float* X = x + (size_t)im * NFULL;
  float* O = out + (size_t)im * NFULL;
  __shared__ unsigned short XT[128 * 128];   // swizzled: byte ^ (((n>>2)&15)<<4)
  __shared__ float c0l[128];
  const int t = threadIdx.x;
  if (t < 128) c0l[t] = c0v[pb * CC + t];
#pragma unroll
  for (int p = 0; p < 8; ++p) {
    int d0 = 2 * (t >> 4) + 32 * (p & 3);
    int n4 = (t & 15) * 4 + 64 * (p >> 2);
    f32x4 x0 = *(const f32x4*)(X + (size_t)d0 * NSP + n0 + n4);
    f32x4 x1 = *(const f32x4*)(X + (size_t)(d0 + 1) * NSP + n0 + n4);
#pragma unroll
    for (int i = 0; i < 4; ++i) {
      int n = n4 + i;
      __hip_bfloat162 h2 = __float22bfloat162_rn(make_float2(x0[i], x1[i]));
      unsigned pk = *reinterpret_cast<unsigned*>(&h2);
      int off = (n * 256 + d0 * 2) ^ (((n >> 2) & 15) << 4);
      *(unsigned*)((char*)XT + off) = pk;
    }
  }
  __syncthreads();

  const int w = t >> 6, l = t & 63;
  const int ln = l & 15, lg = l >> 4;
#pragma unroll
  for (int h = 0; h < 2; ++h) {
    const unsigned short* Pg = Pbf + (size_t)pb * (CC * CC)
                             + (size_t)(h * 64 + ln) * CC + lg * 8;
    s16x8 Af[4][4];
#pragma unroll
    for (int a = 0; a < 4; ++a)
#pragma unroll
      for (int kk = 0; kk < 4; ++kk)
        Af[a][kk] = *(const s16x8*)(Pg + a * 16 * CC + kk * 32);
#pragma unroll
    for (int sub = 0; sub < 2; ++sub) {
      int row = sub * 64 + w * 16 + ln;
      int sw = ((row >> 2) & 15) << 4;
      s16x8 bf[4];
#pragma unroll
      for (int kk = 0; kk < 4; ++kk)
        bf[kk] = *(const s16x8*)((char*)XT + ((row * 256 + kk * 64 + lg * 16) ^ sw));
      f32x4 acc[4];
#pragma unroll
      for (int a = 0; a < 4; ++a) acc[a] = (f32x4){0.f, 0.f, 0.f, 0.f};
#pragma unroll
      for (int kk = 0; kk < 4; ++kk)
#pragma unroll
        for (int a = 0; a < 4; ++a)
          acc[a] = __builtin_amdgcn_mfma_f32_16x16x32_bf16(Af[a][kk], bf[kk], acc[a], 0, 0, 0);
      int n = n0 + sub * 64 + w * 16 + ln;
#pragma unroll
      for (int a = 0; a < 4; ++a)
#pragma unroll
        for (int r = 0; r < 4; ++r) {
          int c = h * 64 + a * 16 + lg * 4 + r;
          __builtin_nontemporal_store(acc[a][r] + c0l[c], O + (size_t)c * NSP + n);
        }
    }
  }
}

// ---------------------------------------------------------------------------
extern "C" void kernel_launch(void* const* d_in, const int* in_sizes, int n_in,
                              void* d_out, int out_size, void* d_ws, size_t ws_size,
                              hipStream_t stream) {
  (void)in_sizes; (void)n_in; (void)out_size;
  const float* x  = (const float*)d_in[0];
  const float* qw = (const float*)d_in[1];
  const float* qb = (const float*)d_in[2];
  const float* kw = (const float*)d_in[3];
  const float* kb = (const float*)d_in[4];
  const float* vw = (const float*)d_in[5];
  const float* vb = (const float*)d_in[6];
  float* out = (float*)d_out;
  float* ws = (float*)d_ws;
  float* M   = ws;                       // 8*128*128  (M, rs, rt contiguous)
  float* rs  = M + 131072;               // 8*128
  float* rt  = rs + 1024;
  float* AST = rt + 1024;                // 8*128*128
  float* ATS = AST + 131072;
  unsigned short* Pbf = (unsigned short*)(ATS + 131072);  // 8*128*128 bf16
  float* c0v = ATS + 131072 + 65536;
  float* Mpart = c0v + 1024;
  const size_t base_floats = (size_t)(Mpart - ws);

  int NB, mode;
  if (ws_size >= (base_floats + (size_t)64 * (131072 + 2048)) * 4) { NB = 64; mode = 0; }
  else if (ws_size >= (base_floats + (size_t)32 * (131072 + 2048)) * 4) { NB = 32; mode = 0; }
  else { NB = 32; mode = 1; }
  const int nst = (16384 / NB) / 64;     // 64-n stages per chunk
  float* rtpart = Mpart + (size_t)NB * 131072;   // NB*8*128
  float* rspart = rtpart + (size_t)NB * 1024;    // NB*8*128

  if (mode == 1) zerok<<<(133120 + 255) / 256, 256, 0, stream>>>(M, 133120);
  k1_mfma<<<dim3(NB, 8), 256, 0, stream>>>(x, mode ? M : Mpart, rs, rt,
                                           rspart, rtpart, nst, mode);
  if (mode == 0)
    k1_reduce<<<130, 256, 0, stream>>>(Mpart, rspart, rtpart, M, rs, rt, NB);
  k2ab<<<dim3(16, 8), 256, 0, stream>>>(M, qw, kw, qb, kb, rs, rt, AST, ATS);
  k2cd<<<dim3(16, 8), 256, 0, stream>>>(AST, ATS, vw, vb, Pbf, c0v);
  k3_mfma<<<dim3(128, 16), 256, 0, stream>>>(x, Pbf, c0v, out);
}

// Round 11
// 149.453 us; speedup vs baseline: 1.1094x; 1.1094x over previous
//
#include <hip/hip_runtime.h>
#include <hip/hip_bf16.h>

#define CC 128
#define NSP 16384              // 128*128 spatial
#define NFULL (CC * NSP)

typedef float f32x4 __attribute__((ext_vector_type(4)));
typedef short s16x8 __attribute__((ext_vector_type(8)));
typedef unsigned int u32x4 __attribute__((ext_vector_type(4)));

__device__ __forceinline__ unsigned bf16rne(float f) {
  unsigned u = __float_as_uint(f);
  return ((u + 0x7FFFu + ((u >> 16) & 1u)) >> 16) & 0xFFFFu;
}

// RNE hi/lo split of a float pair -> packed {hi, lo} u32 (bf16x2 each)
__device__ __forceinline__ uint2 packpair(float x0, float x1) {
  __hip_bfloat162 h2 = __float22bfloat162_rn(make_float2(x0, x1));
  unsigned hu = *reinterpret_cast<unsigned*>(&h2);   // lo16=bf16(x0), hi16=bf16(x1)
  float hf0 = __uint_as_float(hu << 16);
  float hf1 = __uint_as_float(hu & 0xFFFF0000u);
  __hip_bfloat162 l2 = __float22bfloat162_rn(make_float2(x0 - hf0, x1 - hf1));
  unsigned lu = *reinterpret_cast<unsigned*>(&l2);
  return make_uint2(hu, lu);
}

// zero M/rs/rt (mode-1 fallback only)
__global__ __launch_bounds__(256) void zerok(float* __restrict__ p, int n) {
  int i = blockIdx.x * 256 + threadIdx.x;
  if (i < n) p[i] = 0.f;
}

// ---------------------------------------------------------------------------
// K1 (MFMA, LDS-staged, 4 waves, SW-pipelined): per (chunk,b): partial
// Xt*Xs^T over 64-n stages. Next-stage global loads are ISSUED before the
// MFMA phase (T14 split) so HBM latency hides under ~96 MFMA; the vmcnt
// wait lands at the next stage's convert. Convert-once hi/lo bf16 staging
// in XOR-swizzled LDS.
// ---------------------------------------------------------------------------
__global__ __launch_bounds__(256, 2) void k1_mfma(const float* __restrict__ x,
    float* __restrict__ Mdst, float* __restrict__ rs, float* __restrict__ rt,
    float* __restrict__ rspart, float* __restrict__ rtpart,
    int nst, int mode) {
  const int b = blockIdx.y;
  const int chunk = blockIdx.x;
  const int n0 = chunk * (nst * 64);
  const int t = threadIdx.x;
  const int w = t >> 6, l = t & 63;
  const int wr = w >> 1, wc = w & 1;
  const int lr = l & 15, lg = l >> 4;
  const int r0 = t >> 2;               // staging row 0..63 (and +64)
  const int q = t & 3;                 // staging n-quarter (16 floats)
  __shared__ unsigned short Ahi[128 * 64];   // 16KB each, swz: byte^((row&7)<<4)
  __shared__ unsigned short Alo[128 * 64];
  __shared__ unsigned short Bhi[128 * 64];
  __shared__ unsigned short Blo[128 * 64];
  const float* Xs = x + (size_t)b * NFULL;
  const float* Xt = x + (size_t)(b + 8) * NFULL;
  const float* Ar0 = Xt + (size_t)r0 * NSP + q * 16;
  const float* Ar1 = Xt + (size_t)(r0 + 64) * NSP + q * 16;
  const float* Br0 = Xs + (size_t)r0 * NSP + q * 16;
  const float* Br1 = Xs + (size_t)(r0 + 64) * NSP + q * 16;

  f32x4 acc[4][4];
#pragma unroll
  for (int a = 0; a < 4; ++a)
#pragma unroll
    for (int bb = 0; bb < 4; ++bb) acc[a][bb] = (f32x4){0.f, 0.f, 0.f, 0.f};
  float rtp[2] = {0.f, 0.f}, rsp[2] = {0.f, 0.f};

  f32x4 pa0[4], pa1[4], pb0[4], pb1[4];   // prefetched stage (in flight)
#pragma unroll
  for (int i = 0; i < 4; ++i) {
    pa0[i] = *(const f32x4*)(Ar0 + n0 + i * 4);
    pa1[i] = *(const f32x4*)(Ar1 + n0 + i * 4);
    pb0[i] = *(const f32x4*)(Br0 + n0 + i * 4);
    pb1[i] = *(const f32x4*)(Br1 + n0 + i * 4);
  }

  for (int s = 0; s < nst; ++s) {
    __syncthreads();                   // prev-stage LDS reads done
    // convert prefetched regs -> LDS (+ row sums)
#pragma unroll
    for (int p = 0; p < 2; ++p) {
      const int row = r0 + 64 * p;
      const f32x4* av = p ? pa1 : pa0;
      const f32x4* bv = p ? pb1 : pb0;
#pragma unroll
      for (int i = 0; i < 4; ++i) {
        rtp[p] += (av[i][0] + av[i][1]) + (av[i][2] + av[i][3]);
        rsp[p] += (bv[i][0] + bv[i][1]) + (bv[i][2] + bv[i][3]);
      }
      u32x4 h0, l0, h1, l1;
#pragma unroll
      for (int i = 0; i < 2; ++i) {
        uint2 r1 = packpair(av[i][0], av[i][1]);
        h0[2 * i] = r1.x; l0[2 * i] = r1.y;
        uint2 r2 = packpair(av[i][2], av[i][3]);
        h0[2 * i + 1] = r2.x; l0[2 * i + 1] = r2.y;
        uint2 r3 = packpair(av[2 + i][0], av[2 + i][1]);
        h1[2 * i] = r3.x; l1[2 * i] = r3.y;
        uint2 r4 = packpair(av[2 + i][2], av[2 + i][3]);
        h1[2 * i + 1] = r4.x; l1[2 * i + 1] = r4.y;
      }
      {
        int base = row * 128 + q * 32;
        int sw = (row & 7) << 4;
        *(u32x4*)((char*)Ahi + ((base) ^ sw)) = h0;
        *(u32x4*)((char*)Ahi + ((base + 16) ^ sw)) = h1;
        *(u32x4*)((char*)Alo + ((base) ^ sw)) = l0;
        *(u32x4*)((char*)Alo + ((base + 16) ^ sw)) = l1;
      }
#pragma unroll
      for (int i = 0; i < 2; ++i) {
        uint2 r1 = packpair(bv[i][0], bv[i][1]);
        h0[2 * i] = r1.x; l0[2 * i] = r1.y;
        uint2 r2 = packpair(bv[i][2], bv[i][3]);
        h0[2 * i + 1] = r2.x; l0[2 * i + 1] = r2.y;
        uint2 r3 = packpair(bv[2 + i][0], bv[2 + i][1]);
        h1[2 * i] = r3.x; l1[2 * i] = r3.y;
        uint2 r4 = packpair(bv[2 + i][2], bv[2 + i][3]);
        h1[2 * i + 1] = r4.x; l1[2 * i + 1] = r4.y;
      }
      {
        int base = row * 128 + q * 32;
        int sw = (row & 7) << 4;
        *(u32x4*)((char*)Bhi + ((base) ^ sw)) = h0;
        *(u32x4*)((char*)Bhi + ((base + 16) ^ sw)) = h1;
        *(u32x4*)((char*)Blo + ((base) ^ sw)) = l0;
        *(u32x4*)((char*)Blo + ((base + 16) ^ sw)) = l1;
      }
    }
    __syncthreads();                   // LDS ready
    // issue NEXT stage loads before MFMA (latency hides under matrix work)
    if (s + 1 < nst) {
      const int nb = n0 + (s + 1) * 64;
#pragma unroll
      for (int i = 0; i < 4; ++i) {
        pa0[i] = *(const f32x4*)(Ar0 + nb + i * 4);
        pa1[i] = *(const f32x4*)(Ar1 + nb + i * 4);
        pb0[i] = *(const f32x4*)(Br0 + nb + i * 4);
        pb1[i] = *(const f32x4*)(Br1 + nb + i * 4);
      }
    }
#pragma unroll
    for (int kk = 0; kk < 2; ++kk) {
      s16x8 ah[4], al[4], bh[4], bl[4];
#pragma unroll
      for (int a = 0; a < 4; ++a) {
        int row = wr * 64 + a * 16 + lr;
        int off = (row * 128 + kk * 64 + lg * 16) ^ ((row & 7) << 4);
        ah[a] = *(const s16x8*)((char*)Ahi + off);
        al[a] = *(const s16x8*)((char*)Alo + off);
      }
#pragma unroll
      for (int bb = 0; bb < 4; ++bb) {
        int row = wc * 64 + bb * 16 + lr;
        int off = (row * 128 + kk * 64 + lg * 16) ^ ((row & 7) << 4);
        bh[bb] = *(const s16x8*)((char*)Bhi + off);
        bl[bb] = *(const s16x8*)((char*)Blo + off);
      }
#pragma unroll
      for (int a = 0; a < 4; ++a)
#pragma unroll
        for (int bb = 0; bb < 4; ++bb) {
          acc[a][bb] = __builtin_amdgcn_mfma_f32_16x16x32_bf16(ah[a], bh[bb], acc[a][bb], 0, 0, 0);
          acc[a][bb] = __builtin_amdgcn_mfma_f32_16x16x32_bf16(ah[a], bl[bb], acc[a][bb], 0, 0, 0);
          acc[a][bb] = __builtin_amdgcn_mfma_f32_16x16x32_bf16(al[a], bh[bb], acc[a][bb], 0, 0, 0);
        }
    }
  }

  // row-sum reduce over the 4 n-quarters (q = lane&3)
#pragma unroll
  for (int p = 0; p < 2; ++p) {
    float vt = rtp[p];
    vt += __shfl_xor(vt, 1);
    vt += __shfl_xor(vt, 2);
    float vs = rsp[p];
    vs += __shfl_xor(vs, 1);
    vs += __shfl_xor(vs, 2);
    if (q == 0) {
      int row = r0 + 64 * p;
      if (mode == 0) {
        rtpart[((size_t)chunk * 8 + b) * CC + row] = vt;
        rspart[((size_t)chunk * 8 + b) * CC + row] = vs;
      } else {
        atomicAdd(&rt[b * CC + row], vt);
        atomicAdd(&rs[b * CC + row], vs);
      }
    }
  }

  const int rquad = lg << 2;
  if (mode == 0) {
    float* Mp = Mdst + ((size_t)chunk * 8 + b) * (CC * CC);
#pragma unroll
    for (int a = 0; a < 4; ++a)
#pragma unroll
      for (int bb = 0; bb < 4; ++bb)
#pragma unroll
        for (int r = 0; r < 4; ++r) {
          int i = wr * 64 + a * 16 + rquad + r;
          int j = wc * 64 + bb * 16 + lr;
          Mp[i * CC + j] = acc[a][bb][r];
        }
  } else {
    float* Mp = Mdst + (size_t)b * (CC * CC);
#pragma unroll
    for (int a = 0; a < 4; ++a)
#pragma unroll
      for (int bb = 0; bb < 4; ++bb)
#pragma unroll
        for (int r = 0; r < 4; ++r) {
          int i = wr * 64 + a * 16 + rquad + r;
          int j = wc * 64 + bb * 16 + lr;
          atomicAdd(&Mp[i * CC + j], acc[a][bb][r]);
        }
  }
}

// Sum partials, vectorized. Blocks [0,128): M. Block 128: rt. Block 129: rs.
__global__ __launch_bounds__(256) void k1_reduce(const float* __restrict__ Mpart,
    const float* __restrict__ rspart, const float* __restrict__ rtpart,
    float* __restrict__ M, float* __restrict__ rs, float* __restrict__ rt,
    int NB) {
  const int t = threadIdx.x;
  if (blockIdx.x < 128) {
    const int i4 = blockIdx.x * 256 + t;     // < 32768
    const int b = i4 >> 12;
    const int e = (i4 & 4095) * 4;
    f32x4 s = (f32x4){0.f, 0.f, 0.f, 0.f};
    for (int c = 0; c < NB; ++c) {
      f32x4 v = *(const f32x4*)(Mpart + ((size_t)c * 8 + b) * (CC * CC) + e);
      s += v;
    }
    *(f32x4*)(M + (size_t)b * CC * CC + e) = s;
  } else if (blockIdx.x == 128) {
    const int e = t * 4;                      // < 1024
    f32x4 s = (f32x4){0.f, 0.f, 0.f, 0.f};
    for (int c = 0; c < NB; ++c) s += *(const f32x4*)(rtpart + (size_t)c * 1024 + e);
    *(f32x4*)(rt + e) = s;
  } else {
    const int e = t * 4;
    f32x4 s = (f32x4){0.f, 0.f, 0.f, 0.f};
    for (int c = 0; c < NB; ++c) s += *(const f32x4*)(rspart + (size_t)c * 1024 + e);
    *(f32x4*)(rs + e) = s;
  }
}

// ---------------------------------------------------------------------------
// K2ab fused: T1=Wq*M, T2=Wq*M^T, us/ut, G + softmax (st & ts).
// grid (16 c-groups of 8 rows, 8 b). Cols strided: lane L owns {L+32j}.
// ---------------------------------------------------------------------------
__global__ __launch_bounds__(256) void k2ab(const float* __restrict__ M,
    const float* __restrict__ qw, const float* __restrict__ kw,
    const float* __restrict__ qb, const float* __restrict__ kb,
    const float* __restrict__ rs, const float* __restrict__ rt,
    float* __restrict__ Ast, float* __restrict__ Ats) {
  const int b = blockIdx.y;
  const int c0 = blockIdx.x * 8;
  __shared__ float Big[128][132];      // M, later Wk (132: 16B-aligned rows)
  __shared__ float Wq[8][128];
  __shared__ float T12[2][8][128];
  __shared__ float uvv[2][8];
  __shared__ float wv2[2][128];
  const int t = threadIdx.x;
  const float* Mb = M + (size_t)b * CC * CC;
#pragma unroll
  for (int p = 0; p < 16; ++p) {
    int f = p * 256 + t;
    int row = f >> 5, c4 = (f & 31) * 4;
    *(f32x4*)&Big[row][c4] = *(const f32x4*)(Mb + row * CC + c4);
  }
  { int row = t >> 5, c4 = (t & 31) * 4;
    *(f32x4*)&Wq[row][c4] = *(const f32x4*)(qw + (c0 + row) * CC + c4); }
  __syncthreads();
  if (t < 16) {
    int c = t & 7;
    const float* r = ((t < 8) ? rs : rt) + b * CC;
    float s = 0.f;
    for (int i = 0; i < CC; ++i) s += Wq[c][i] * r[i];
    uvv[(t < 8) ? 1 : 0][c] = s;       // us->[1], ut->[0]
  }
  const int tr = t >> 5;               // row 0..7
  const int L = t & 31;                // col lane
  {
    float a1[4] = {0.f, 0.f, 0.f, 0.f}, a2[4] = {0.f, 0.f, 0.f, 0.f};
    for (int i = 0; i < CC; ++i) {
      float wq = Wq[tr][i];
#pragma unroll
      for (int j = 0; j < 4; ++j) a1[j] += wq * Big[i][L + 32 * j];
    }
    for (int i4 = 0; i4 < 32; ++i4) {
      f32x4 wq4 = *(const f32x4*)&Wq[tr][i4 * 4];
#pragma unroll
      for (int j = 0; j < 4; ++j) {
        f32x4 m4 = *(const f32x4*)&Big[L + 32 * j][i4 * 4];
        a2[j] += wq4[0]*m4[0] + wq4[1]*m4[1] + wq4[2]*m4[2] + wq4[3]*m4[3];
      }
    }
#pragma unroll
    for (int j = 0; j < 4; ++j) {
      T12[0][tr][L + 32 * j] = a1[j];
      T12[1][tr][L + 32 * j] = a2[j];
    }
  }
  __syncthreads();
  // overwrite Big with Wk
#pragma unroll
  for (int p = 0; p < 16; ++p) {
    int f = p * 256 + t;
    int row = f >> 5, c4 = (f & 31) * 4;
    *(f32x4*)&Big[row][c4] = *(const f32x4*)(kw + row * CC + c4);
  }
  __syncthreads();
  {
    int d = t & 127, wh = t >> 7;      // 0: rs, 1: rt
    const float* r = (wh ? rt : rs) + b * CC;
    float s = 0.f;
    for (int i4 = 0; i4 < 32; ++i4) {
      f32x4 w4 = *(const f32x4*)&Big[d][i4 * 4];
      s += w4[0]*r[i4*4] + w4[1]*r[i4*4+1] + w4[2]*r[i4*4+2] + w4[3]*r[i4*4+3];
    }
    wv2[wh][d] = s;
  }
  __syncthreads();
  const int c = c0 + tr;
  const float bqc = qb[c];
#pragma unroll 1
  for (int which = 0; which < 2; ++which) {
    float g[4];
#pragma unroll
    for (int j = 0; j < 4; ++j) {
      int d = L + 32 * j;
      g[j] = uvv[which][tr] * kb[d] + bqc * wv2[which][d] + 16384.f * bqc * kb[d];
    }
    for (int j4 = 0; j4 < 32; ++j4) {
      f32x4 tv4 = *(const f32x4*)&T12[which][tr][j4 * 4];
#pragma unroll
      for (int j = 0; j < 4; ++j) {
        f32x4 w4 = *(const f32x4*)&Big[L + 32 * j][j4 * 4];
        g[j] += tv4[0]*w4[0] + tv4[1]*w4[1] + tv4[2]*w4[2] + tv4[3]*w4[3];
      }
    }
    float m = fmaxf(fmaxf(g[0], g[1]), fmaxf(g[2], g[3]));
#pragma unroll
    for (int off = 1; off < 32; off <<= 1) m = fmaxf(m, __shfl_xor(m, off));
    float s = 0.f;
#pragma unroll
    for (int j = 0; j < 4; ++j) { g[j] = expf(g[j] - m); s += g[j]; }
#pragma unroll
    for (int off = 1; off < 32; off <<= 1) s += __shfl_xor(s, off);
    const float inv = 1.f / s;
    float* A = (which ? Ats : Ast) + (size_t)b * CC * CC + (size_t)c * CC;
#pragma unroll
    for (int j = 0; j < 4; ++j) A[L + 32 * j] = g[j] * inv;
  }
}

// ---------------------------------------------------------------------------
// K2cd fused: L = Ast*Ats^T, softmax -> Att, P' = Att*Wv + I (bf16), c0.
// grid (16 c-groups of 8 rows, 8 b).
// ---------------------------------------------------------------------------
__global__ __launch_bounds__(256) void k2cd(const float* __restrict__ Ast,
    const float* __restrict__ Ats, const float* __restrict__ vw,
    const float* __restrict__ vb, unsigned short* __restrict__ Pbf,
    float* __restrict__ c0v) {
  const int b = blockIdx.y;
  const int c0 = blockIdx.x * 8;
  __shared__ float Big[128][132];      // Ats, later Wv[d][i]
  __shared__ float Tl[8][128];
  __shared__ float Al[8][128];
  const int t = threadIdx.x;
  const float* Bb = Ats + (size_t)b * CC * CC;
  const float* Tb = Ast + (size_t)b * CC * CC;
#pragma unroll
  for (int p = 0; p < 16; ++p) {
    int f = p * 256 + t;
    int row = f >> 5, c4 = (f & 31) * 4;
    *(f32x4*)&Big[row][c4] = *(const f32x4*)(Bb + row * CC + c4);
  }
  { int row = t >> 5, c4 = (t & 31) * 4;
    *(f32x4*)&Tl[row][c4] = *(const f32x4*)(Tb + (c0 + row) * CC + c4); }
  __syncthreads();
  const int tr = t >> 5;
  const int L = t & 31;
  {
    float g[4] = {0.f, 0.f, 0.f, 0.f};
    for (int e4 = 0; e4 < 32; ++e4) {
      f32x4 tv4 = *(const f32x4*)&Tl[tr][e4 * 4];
#pragma unroll
      for (int j = 0; j < 4; ++j) {
        f32x4 a4 = *(const f32x4*)&Big[L + 32 * j][e4 * 4];
        g[j] += tv4[0]*a4[0] + tv4[1]*a4[1] + tv4[2]*a4[2] + tv4[3]*a4[3];
      }
    }
    float m = fmaxf(fmaxf(g[0], g[1]), fmaxf(g[2], g[3]));
#pragma unroll
    for (int off = 1; off < 32; off <<= 1) m = fmaxf(m, __shfl_xor(m, off));
    float s = 0.f;
#pragma unroll
    for (int j = 0; j < 4; ++j) { g[j] = expf(g[j] - m); s += g[j]; }
#pragma unroll
    for (int off = 1; off < 32; off <<= 1) s += __shfl_xor(s, off);
    const float inv = 1.f / s;
#pragma unroll
    for (int j = 0; j < 4; ++j) Al[tr][L + 32 * j] = g[j] * inv;
  }
  __syncthreads();
  // overwrite Big with Wv[d][i]
#pragma unroll
  for (int p = 0; p < 16; ++p) {
    int f = p * 256 + t;
    int row = f >> 5, c4 = (f & 31) * 4;
    *(f32x4*)&Big[row][c4] = *(const f32x4*)(vw + row * CC + c4);
  }
  __syncthreads();
  float p4[4] = {0.f, 0.f, 0.f, 0.f};
  for (int d = 0; d < CC; ++d) {
    float av = Al[tr][d];
#pragma unroll
    for (int j = 0; j < 4; ++j) p4[j] += av * Big[d][L + 32 * j];
  }
  float csum = 0.f;
#pragma unroll
  for (int j = 0; j < 4; ++j) csum += Al[tr][L + 32 * j] * vb[L + 32 * j];
#pragma unroll
  for (int off = 1; off < 32; off <<= 1) csum += __shfl_xor(csum, off);
  const int c = c0 + tr;
  if ((c & 31) == L) p4[c >> 5] += 1.0f;      // P' = P + I (residual folded in)
  unsigned short* Pp = Pbf + (size_t)b * CC * CC + (size_t)c * CC;
#pragma unroll
  for (int j = 0; j < 4; ++j) Pp[L + 32 * j] = (unsigned short)bf16rne(p4[j]);
  if (L == 0) c0v[b * CC + c] = csum;
}

// ---------------------------------------------------------------------------
// K3 (MFMA): out[c][n] = sum_e P'[c][e]*x[e][n] + c0[c]  (identity in P').
// 256-n tile per block staged ONCE to LDS (transposed bf16, swizzled);
// P' fragments hoisted to registers per c-half and reused across 4 subtiles.
// Output via nontemporal stores. grid (64 n-tiles, 16 images), 4 waves.
// ---------------------------------------------------------------------------
__global__ __launch_bounds__(256, 2) void k3_mfma(const float* __restrict__ x,
    const unsigned short* __restrict__ Pbf, const float* __restrict__ c0v,
    float* __restrict__ out) {
  const int im = blockIdx.y;
  const int pb = im & 7;
  const int n0 = blockIdx.x * 256;
  const float* X = x + (size_t)im * NFULL;
  float* O = out + (size_t)im * NFULL;
  __shared__ unsigned short XT[256 * 128];   // swizzled: byte ^ (((n>>2)&15)<<4)
  __shared__ float c0l[128];
  const int t = threadIdx.x;
  if (t < 128) c0l[t] = c0v[pb * CC + t];
#pragma unroll
  for (int p = 0; p < 16; ++p) {
    int d0 = 2 * (t >> 4) + 32 * (p & 3);
    int n4 = (t & 15) * 4 + 64 * (p >> 2);
    f32x4 x0 = *(const f32x4*)(X + (size_t)d0 * NSP + n0 + n4);
    f32x4 x1 = *(const f32x4*)(X + (size_t)(d0 + 1) * NSP + n0 + n4);
#pragma unroll
    for (int i = 0; i < 4; ++i) {
      int n = n4 + i;
      __hip_bfloat162 h2 = __float22bfloat162_rn(make_float2(x0[i], x1[i]));
      unsigned pk = *reinterpret_cast<unsigned*>(&h2);
      int off = (n * 256 + d0 * 2) ^ (((n >> 2) & 15) << 4);
      *(unsigned*)((char*)XT + off) = pk;
    }
  }
  __syncthreads();

  const int w = t >> 6, l = t & 63;
  const int ln = l & 15, lg = l >> 4;
#pragma unroll
  for (int h = 0; h < 2; ++h) {
    const unsigned short* Pg = Pbf + (size_t)pb * (CC * CC)
                             + (size_t)(h * 64 + ln) * CC + lg * 8;
    s16x8 Af[4][4];
#pragma unroll
    for (int a = 0; a < 4; ++a)
#pragma unroll
      for (int kk = 0; kk < 4; ++kk)
        Af[a][kk] = *(const s16x8*)(Pg + a * 16 * CC + kk * 32);
#pragma unroll
    for (int sub = 0; sub < 4; ++sub) {
      int row = sub * 64 + w * 16 + ln;
      int sw = ((row >> 2) & 15) << 4;
      s16x8 bf[4];
#pragma unroll
      for (int kk = 0; kk < 4; ++kk)
        bf[kk] = *(const s16x8*)((char*)XT + ((row * 256 + kk * 64 + lg * 16) ^ sw));
      f32x4 acc[4];
#pragma unroll
      for (int a = 0; a < 4; ++a) acc[a] = (f32x4){0.f, 0.f, 0.f, 0.f};
#pragma unroll
      for (int kk = 0; kk < 4; ++kk)
#pragma unroll
        for (int a = 0; a < 4; ++a)
          acc[a] = __builtin_amdgcn_mfma_f32_16x16x32_bf16(Af[a][kk], bf[kk], acc[a], 0, 0, 0);
      int n = n0 + sub * 64 + w * 16 + ln;
#pragma unroll
      for (int a = 0; a < 4; ++a)
#pragma unroll
        for (int r = 0; r < 4; ++r) {
          int c = h * 64 + a * 16 + lg * 4 + r;
          __builtin_nontemporal_store(acc[a][r] + c0l[c], O + (size_t)c * NSP + n);
        }
    }
  }
}

// ---------------------------------------------------------------------------
extern "C" void kernel_launch(void* const* d_in, const int* in_sizes, int n_in,
                              void* d_out, int out_size, void* d_ws, size_t ws_size,
                              hipStream_t stream) {
  (void)in_sizes; (void)n_in; (void)out_size;
  const float* x  = (const float*)d_in[0];
  const float* qw = (const float*)d_in[1];
  const float* qb = (const float*)d_in[2];
  const float* kw = (const float*)d_in[3];
  const float* kb = (const float*)d_in[4];
  const float* vw = (const float*)d_in[5];
  const float* vb = (const float*)d_in[6];
  float* out = (float*)d_out;
  float* ws = (float*)d_ws;
  float* M   = ws;                       // 8*128*128  (M, rs, rt contiguous)
  float* rs  = M + 131072;               // 8*128
  float* rt  = rs + 1024;
  float* AST = rt + 1024;                // 8*128*128
  float* ATS = AST + 131072;
  unsigned short* Pbf = (unsigned short*)(ATS + 131072);  // 8*128*128 bf16
  float* c0v = ATS + 131072 + 65536;
  float* Mpart = c0v + 1024;
  const size_t base_floats = (size_t)(Mpart - ws);

  int NB, mode;
  if (ws_size >= (base_floats + (size_t)64 * (131072 + 2048)) * 4) { NB = 64; mode = 0; }
  else if (ws_size >= (base_floats + (size_t)32 * (131072 + 2048)) * 4) { NB = 32; mode = 0; }
  else { NB = 32; mode = 1; }
  const int nst = (16384 / NB) / 64;     // 64-n stages per chunk
  float* rtpart = Mpart + (size_t)NB * 131072;   // NB*8*128
  float* rspart = rtpart + (size_t)NB * 1024;    // NB*8*128

  if (mode == 1) zerok<<<(133120 + 255) / 256, 256, 0, stream>>>(M, 133120);
  k1_mfma<<<dim3(NB, 8), 256, 0, stream>>>(x, mode ? M : Mpart, rs, rt,
                                           rspart, rtpart, nst, mode);
  if (mode == 0)
    k1_reduce<<<130, 256, 0, stream>>>(Mpart, rspart, rtpart, M, rs, rt, NB);
  k2ab<<<dim3(16, 8), 256, 0, stream>>>(M, qw, kw, qb, kb, rs, rt, AST, ATS);
  k2cd<<<dim3(16, 8), 256, 0, stream>>>(AST, ATS, vw, vb, Pbf, c0v);
  k3_mfma<<<dim3(64, 16), 256, 0, stream>>>(x, Pbf, c0v, out);
}

// Round 12
// 147.236 us; speedup vs baseline: 1.1261x; 1.0151x over previous
//
#include <hip/hip_runtime.h>
#include <hip/hip_bf16.h>

#define CC 128
#define NSP 16384              // 128*128 spatial
#define NFULL (CC * NSP)

typedef float f32x4 __attribute__((ext_vector_type(4)));
typedef short s16x8 __attribute__((ext_vector_type(8)));
typedef unsigned int u32x4 __attribute__((ext_vector_type(4)));

#define GLOAD16(g, l) __builtin_amdgcn_global_load_lds( \
    (const __attribute__((address_space(1))) void*)(g), \
    (__attribute__((address_space(3))) void*)(l), 16, 0, 0)

__device__ __forceinline__ unsigned bf16rne(float f) {
  unsigned u = __float_as_uint(f);
  return ((u + 0x7FFFu + ((u >> 16) & 1u)) >> 16) & 0xFFFFu;
}

// RNE hi/lo split of a float pair -> packed {hi, lo} u32 (bf16x2 each)
__device__ __forceinline__ uint2 packpair(float x0, float x1) {
  __hip_bfloat162 h2 = __float22bfloat162_rn(make_float2(x0, x1));
  unsigned hu = *reinterpret_cast<unsigned*>(&h2);   // lo16=bf16(x0), hi16=bf16(x1)
  float hf0 = __uint_as_float(hu << 16);
  float hf1 = __uint_as_float(hu & 0xFFFF0000u);
  __hip_bfloat162 l2 = __float22bfloat162_rn(make_float2(x0 - hf0, x1 - hf1));
  unsigned lu = *reinterpret_cast<unsigned*>(&l2);
  return make_uint2(hu, lu);
}

// zero M/rs/rt (mode-1 fallback only)
__global__ __launch_bounds__(256) void zerok(float* __restrict__ p, int n) {
  int i = blockIdx.x * 256 + threadIdx.x;
  if (i < n) p[i] = 0.f;
}

// ---------------------------------------------------------------------------
// K1 (MFMA, global_load_lds staged): per (chunk,b): partial Xt*Xs^T over
// 32-n stages. Raw f32 tiles go DIRECTLY to LDS via global_load_lds (16B,
// no VGPR round-trip): 8 x 1KB in flight per wave = 64KB/CU -> Little's-law
// satisfied. Double-buffered 2x32KB; one barrier per stage; next stage is
// issued before the MFMA phase so the barrier's vmcnt drain is free.
// bf16 hi/lo conversion happens at fragment-read time (packpair in-reg).
// LDS swizzle per rule #21: linear gload dest + inverse-swz global source
// (n16 = (l&7) ^ (row&7)) + swz read (slot ^ (row&7)) -> 2-way = free.
// ---------------------------------------------------------------------------
__global__ __launch_bounds__(256, 2) void k1_mfma(const float* __restrict__ x,
    float* __restrict__ Mdst, float* __restrict__ rs, float* __restrict__ rt,
    float* __restrict__ rspart, float* __restrict__ rtpart,
    int nst, int mode) {
  const int b = blockIdx.y;
  const int chunk = blockIdx.x;
  const int n0 = chunk * (nst * 32);
  const int t = threadIdx.x;
  const int w = t >> 6, l = t & 63;
  const int wr = w >> 1, wc = w & 1;
  const int lr = l & 15, lg = l >> 4;
  __shared__ __align__(16) char LB[2][2][128 * 128];  // [dbuf][A/B][row*128B] = 64KB
  const float* Xs = x + (size_t)b * NFULL;
  const float* Xt = x + (size_t)(b + 8) * NFULL;
  const int srow0 = w * 32 + (l >> 3);     // staging row base for this lane
  const int sn16x = (l & 7);               // slot index before swizzle

  f32x4 acc[4][4];
#pragma unroll
  for (int a = 0; a < 4; ++a)
#pragma unroll
    for (int bb = 0; bb < 4; ++bb) acc[a][bb] = (f32x4){0.f, 0.f, 0.f, 0.f};
  float rtp[4] = {0.f, 0.f, 0.f, 0.f};
  float rsp[4] = {0.f, 0.f, 0.f, 0.f};

  // prologue: issue stage 0 into buf 0
  {
#pragma unroll
    for (int i = 0; i < 4; ++i) {
      int row = srow0 + i * 8;
      int n16 = sn16x ^ (row & 7);
      GLOAD16(Xt + (size_t)row * NSP + n0 + n16 * 4, &LB[0][0][(w * 32 + i * 8) * 128]);
      GLOAD16(Xs + (size_t)row * NSP + n0 + n16 * 4, &LB[0][1][(w * 32 + i * 8) * 128]);
    }
  }

  for (int s = 0; s < nst; ++s) {
    const int cur = s & 1;
    __syncthreads();                 // vmcnt drain: buf[cur] complete; prev reads done
    if (s + 1 < nst) {               // issue next stage into other buffer (hides under MFMA)
      const int nb = n0 + (s + 1) * 32;
#pragma unroll
      for (int i = 0; i < 4; ++i) {
        int row = srow0 + i * 8;
        int n16 = sn16x ^ (row & 7);
        GLOAD16(Xt + (size_t)row * NSP + nb + n16 * 4, &LB[cur ^ 1][0][(w * 32 + i * 8) * 128]);
        GLOAD16(Xs + (size_t)row * NSP + nb + n16 * 4, &LB[cur ^ 1][1][(w * 32 + i * 8) * 128]);
      }
    }
    const char* A = &LB[cur][0][0];
    const char* B = &LB[cur][1][0];
    s16x8 ah[4], al[4], bh[4], bl[4];
#pragma unroll
    for (int a = 0; a < 4; ++a) {
      int row = wr * 64 + a * 16 + lr;
      int base = row * 128, sw = row & 7;
      f32x4 f0 = *(const f32x4*)(A + base + (((lg * 2) ^ sw) << 4));
      f32x4 f1 = *(const f32x4*)(A + base + (((lg * 2 + 1) ^ sw) << 4));
      rtp[a] += ((f0[0] + f0[1]) + (f0[2] + f0[3])) + ((f1[0] + f1[1]) + (f1[2] + f1[3]));
      uint2 p0 = packpair(f0[0], f0[1]);
      uint2 p1 = packpair(f0[2], f0[3]);
      uint2 p2 = packpair(f1[0], f1[1]);
      uint2 p3 = packpair(f1[2], f1[3]);
      u32x4 H = {p0.x, p1.x, p2.x, p3.x};
      u32x4 L = {p0.y, p1.y, p2.y, p3.y};
      ah[a] = __builtin_bit_cast(s16x8, H);
      al[a] = __builtin_bit_cast(s16x8, L);
    }
#pragma unroll
    for (int bb = 0; bb < 4; ++bb) {
      int row = wc * 64 + bb * 16 + lr;
      int base = row * 128, sw = row & 7;
      f32x4 f0 = *(const f32x4*)(B + base + (((lg * 2) ^ sw) << 4));
      f32x4 f1 = *(const f32x4*)(B + base + (((lg * 2 + 1) ^ sw) << 4));
      rsp[bb] += ((f0[0] + f0[1]) + (f0[2] + f0[3])) + ((f1[0] + f1[1]) + (f1[2] + f1[3]));
      uint2 p0 = packpair(f0[0], f0[1]);
      uint2 p1 = packpair(f0[2], f0[3]);
      uint2 p2 = packpair(f1[0], f1[1]);
      uint2 p3 = packpair(f1[2], f1[3]);
      u32x4 H = {p0.x, p1.x, p2.x, p3.x};
      u32x4 L = {p0.y, p1.y, p2.y, p3.y};
      bh[bb] = __builtin_bit_cast(s16x8, H);
      bl[bb] = __builtin_bit_cast(s16x8, L);
    }
#pragma unroll
    for (int a = 0; a < 4; ++a)
#pragma unroll
      for (int bb = 0; bb < 4; ++bb) {
        acc[a][bb] = __builtin_amdgcn_mfma_f32_16x16x32_bf16(ah[a], bh[bb], acc[a][bb], 0, 0, 0);
        acc[a][bb] = __builtin_amdgcn_mfma_f32_16x16x32_bf16(ah[a], bl[bb], acc[a][bb], 0, 0, 0);
        acc[a][bb] = __builtin_amdgcn_mfma_f32_16x16x32_bf16(al[a], bh[bb], acc[a][bb], 0, 0, 0);
      }
  }

  // row sums: reduce over lg (k-groups) via lanes l^16, l^32.
  // A rows owned by wc==0 waves; B rows by wr==0 waves (each row exactly once).
#pragma unroll
  for (int a = 0; a < 4; ++a) {
    float vt = rtp[a];
    vt += __shfl_xor(vt, 16);
    vt += __shfl_xor(vt, 32);
    float vs = rsp[a];
    vs += __shfl_xor(vs, 16);
    vs += __shfl_xor(vs, 32);
    if (l < 16) {
      if (wc == 0) {
        int row = wr * 64 + a * 16 + l;
        if (mode == 0) rtpart[((size_t)chunk * 8 + b) * CC + row] = vt;
        else atomicAdd(&rt[b * CC + row], vt);
      }
      if (wr == 0) {
        int row = wc * 64 + a * 16 + l;
        if (mode == 0) rspart[((size_t)chunk * 8 + b) * CC + row] = vs;
        else atomicAdd(&rs[b * CC + row], vs);
      }
    }
  }

  const int rquad = lg << 2;
  if (mode == 0) {
    float* Mp = Mdst + ((size_t)chunk * 8 + b) * (CC * CC);
#pragma unroll
    for (int a = 0; a < 4; ++a)
#pragma unroll
      for (int bb = 0; bb < 4; ++bb)
#pragma unroll
        for (int r = 0; r < 4; ++r) {
          int i = wr * 64 + a * 16 + rquad + r;
          int j = wc * 64 + bb * 16 + lr;
          Mp[i * CC + j] = acc[a][bb][r];
        }
  } else {
    float* Mp = Mdst + (size_t)b * (CC * CC);
#pragma unroll
    for (int a = 0; a < 4; ++a)
#pragma unroll
      for (int bb = 0; bb < 4; ++bb)
#pragma unroll
        for (int r = 0; r < 4; ++r) {
          int i = wr * 64 + a * 16 + rquad + r;
          int j = wc * 64 + bb * 16 + lr;
          atomicAdd(&Mp[i * CC + j], acc[a][bb][r]);
        }
  }
}

// Sum partials, vectorized. Blocks [0,128): M. Block 128: rt. Block 129: rs.
__global__ __launch_bounds__(256) void k1_reduce(const float* __restrict__ Mpart,
    const float* __restrict__ rspart, const float* __restrict__ rtpart,
    float* __restrict__ M, float* __restrict__ rs, float* __restrict__ rt,
    int NB) {
  const int t = threadIdx.x;
  if (blockIdx.x < 128) {
    const int i4 = blockIdx.x * 256 + t;     // < 32768
    const int b = i4 >> 12;
    const int e = (i4 & 4095) * 4;
    f32x4 s = (f32x4){0.f, 0.f, 0.f, 0.f};
    for (int c = 0; c < NB; ++c) {
      f32x4 v = *(const f32x4*)(Mpart + ((size_t)c * 8 + b) * (CC * CC) + e);
      s += v;
    }
    *(f32x4*)(M + (size_t)b * CC * CC + e) = s;
  } else if (blockIdx.x == 128) {
    const int e = t * 4;                      // < 1024
    f32x4 s = (f32x4){0.f, 0.f, 0.f, 0.f};
    for (int c = 0; c < NB; ++c) s += *(const f32x4*)(rtpart + (size_t)c * 1024 + e);
    *(f32x4*)(rt + e) = s;
  } else {
    const int e = t * 4;
    f32x4 s = (f32x4){0.f, 0.f, 0.f, 0.f};
    for (int c = 0; c < NB; ++c) s += *(const f32x4*)(rspart + (size_t)c * 1024 + e);
    *(f32x4*)(rs + e) = s;
  }
}

// ---------------------------------------------------------------------------
// K2ab fused: T1=Wq*M, T2=Wq*M^T, us/ut, G + softmax (st & ts).
// grid (16 c-groups of 8 rows, 8 b). Cols strided: lane L owns {L+32j}.
// ---------------------------------------------------------------------------
__global__ __launch_bounds__(256) void k2ab(const float* __restrict__ M,
    const float* __restrict__ qw, const float* __restrict__ kw,
    const float* __restrict__ qb, const float* __restrict__ kb,
    const float* __restrict__ rs, const float* __restrict__ rt,
    float* __restrict__ Ast, float* __restrict__ Ats) {
  const int b = blockIdx.y;
  const int c0 = blockIdx.x * 8;
  __shared__ float Big[128][132];      // M, later Wk (132: 16B-aligned rows)
  __shared__ float Wq[8][128];
  __shared__ float T12[2][8][128];
  __shared__ float uvv[2][8];
  __shared__ float wv2[2][128];
  const int t = threadIdx.x;
  const float* Mb = M + (size_t)b * CC * CC;
#pragma unroll
  for (int p = 0; p < 16; ++p) {
    int f = p * 256 + t;
    int row = f >> 5, c4 = (f & 31) * 4;
    *(f32x4*)&Big[row][c4] = *(const f32x4*)(Mb + row * CC + c4);
  }
  { int row = t >> 5, c4 = (t & 31) * 4;
    *(f32x4*)&Wq[row][c4] = *(const f32x4*)(qw + (c0 + row) * CC + c4); }
  __syncthreads();
  if (t < 16) {
    int c = t & 7;
    const float* r = ((t < 8) ? rs : rt) + b * CC;
    float s = 0.f;
    for (int i = 0; i < CC; ++i) s += Wq[c][i] * r[i];
    uvv[(t < 8) ? 1 : 0][c] = s;       // us->[1], ut->[0]
  }
  const int tr = t >> 5;               // row 0..7
  const int L = t & 31;                // col lane
  {
    float a1[4] = {0.f, 0.f, 0.f, 0.f}, a2[4] = {0.f, 0.f, 0.f, 0.f};
    for (int i = 0; i < CC; ++i) {
      float wq = Wq[tr][i];
#pragma unroll
      for (int j = 0; j < 4; ++j) a1[j] += wq * Big[i][L + 32 * j];
    }
    for (int i4 = 0; i4 < 32; ++i4) {
      f32x4 wq4 = *(const f32x4*)&Wq[tr][i4 * 4];
#pragma unroll
      for (int j = 0; j < 4; ++j) {
        f32x4 m4 = *(const f32x4*)&Big[L + 32 * j][i4 * 4];
        a2[j] += wq4[0]*m4[0] + wq4[1]*m4[1] + wq4[2]*m4[2] + wq4[3]*m4[3];
      }
    }
#pragma unroll
    for (int j = 0; j < 4; ++j) {
      T12[0][tr][L + 32 * j] = a1[j];
      T12[1][tr][L + 32 * j] = a2[j];
    }
  }
  __syncthreads();
  // overwrite Big with Wk
#pragma unroll
  for (int p = 0; p < 16; ++p) {
    int f = p * 256 + t;
    int row = f >> 5, c4 = (f & 31) * 4;
    *(f32x4*)&Big[row][c4] = *(const f32x4*)(kw + row * CC + c4);
  }
  __syncthreads();
  {
    int d = t & 127, wh = t >> 7;      // 0: rs, 1: rt
    const float* r = (wh ? rt : rs) + b * CC;
    float s = 0.f;
    for (int i4 = 0; i4 < 32; ++i4) {
      f32x4 w4 = *(const f32x4*)&Big[d][i4 * 4];
      s += w4[0]*r[i4*4] + w4[1]*r[i4*4+1] + w4[2]*r[i4*4+2] + w4[3]*r[i4*4+3];
    }
    wv2[wh][d] = s;
  }
  __syncthreads();
  const int c = c0 + tr;
  const float bqc = qb[c];
#pragma unroll 1
  for (int which = 0; which < 2; ++which) {
    float g[4];
#pragma unroll
    for (int j = 0; j < 4; ++j) {
      int d = L + 32 * j;
      g[j] = uvv[which][tr] * kb[d] + bqc * wv2[which][d] + 16384.f * bqc * kb[d];
    }
    for (int j4 = 0; j4 < 32; ++j4) {
      f32x4 tv4 = *(const f32x4*)&T12[which][tr][j4 * 4];
#pragma unroll
      for (int j = 0; j < 4; ++j) {
        f32x4 w4 = *(const f32x4*)&Big[L + 32 * j][j4 * 4];
        g[j] += tv4[0]*w4[0] + tv4[1]*w4[1] + tv4[2]*w4[2] + tv4[3]*w4[3];
      }
    }
    float m = fmaxf(fmaxf(g[0], g[1]), fmaxf(g[2], g[3]));
#pragma unroll
    for (int off = 1; off < 32; off <<= 1) m = fmaxf(m, __shfl_xor(m, off));
    float s = 0.f;
#pragma unroll
    for (int j = 0; j < 4; ++j) { g[j] = expf(g[j] - m); s += g[j]; }
#pragma unroll
    for (int off = 1; off < 32; off <<= 1) s += __shfl_xor(s, off);
    const float inv = 1.f / s;
    float* A = (which ? Ats : Ast) + (size_t)b * CC * CC + (size_t)c * CC;
#pragma unroll
    for (int j = 0; j < 4; ++j) A[L + 32 * j] = g[j] * inv;
  }
}

// ---------------------------------------------------------------------------
// K2cd fused: L = Ast*Ats^T, softmax -> Att, P' = Att*Wv + I (bf16), c0.
// grid (16 c-groups of 8 rows, 8 b).
// ---------------------------------------------------------------------------
__global__ __launch_bounds__(256) void k2cd(const float* __restrict__ Ast,
    const float* __restrict__ Ats, const float* __restrict__ vw,
    const float* __restrict__ vb, unsigned short* __restrict__ Pbf,
    float* __restrict__ c0v) {
  const int b = blockIdx.y;
  const int c0 = blockIdx.x * 8;
  __shared__ float Big[128][132];      // Ats, later Wv[d][i]
  __shared__ float Tl[8][128];
  __shared__ float Al[8][128];
  const int t = threadIdx.x;
  const float* Bb = Ats + (size_t)b * CC * CC;
  const float* Tb = Ast + (size_t)b * CC * CC;
#pragma unroll
  for (int p = 0; p < 16; ++p) {
    int f = p * 256 + t;
    int row = f >> 5, c4 = (f & 31) * 4;
    *(f32x4*)&Big[row][c4] = *(const f32x4*)(Bb + row * CC + c4);
  }
  { int row = t >> 5, c4 = (t & 31) * 4;
    *(f32x4*)&Tl[row][c4] = *(const f32x4*)(Tb + (c0 + row) * CC + c4); }
  __syncthreads();
  const int tr = t >> 5;
  const int L = t & 31;
  {
    float g[4] = {0.f, 0.f, 0.f, 0.f};
    for (int e4 = 0; e4 < 32; ++e4) {
      f32x4 tv4 = *(const f32x4*)&Tl[tr][e4 * 4];
#pragma unroll
      for (int j = 0; j < 4; ++j) {
        f32x4 a4 = *(const f32x4*)&Big[L + 32 * j][e4 * 4];
        g[j] += tv4[0]*a4[0] + tv4[1]*a4[1] + tv4[2]*a4[2] + tv4[3]*a4[3];
      }
    }
    float m = fmaxf(fmaxf(g[0], g[1]), fmaxf(g[2], g[3]));
#pragma unroll
    for (int off = 1; off < 32; off <<= 1) m = fmaxf(m, __shfl_xor(m, off));
    float s = 0.f;
#pragma unroll
    for (int j = 0; j < 4; ++j) { g[j] = expf(g[j] - m); s += g[j]; }
#pragma unroll
    for (int off = 1; off < 32; off <<= 1) s += __shfl_xor(s, off);
    const float inv = 1.f / s;
#pragma unroll
    for (int j = 0; j < 4; ++j) Al[tr][L + 32 * j] = g[j] * inv;
  }
  __syncthreads();
  // overwrite Big with Wv[d][i]
#pragma unroll
  for (int p = 0; p < 16; ++p) {
    int f = p * 256 + t;
    int row = f >> 5, c4 = (f & 31) * 4;
    *(f32x4*)&Big[row][c4] = *(const f32x4*)(vw + row * CC + c4);
  }
  __syncthreads();
  float p4[4] = {0.f, 0.f, 0.f, 0.f};
  for (int d = 0; d < CC; ++d) {
    float av = Al[tr][d];
#pragma unroll
    for (int j = 0; j < 4; ++j) p4[j] += av * Big[d][L + 32 * j];
  }
  float csum = 0.f;
#pragma unroll
  for (int j = 0; j < 4; ++j) csum += Al[tr][L + 32 * j] * vb[L + 32 * j];
#pragma unroll
  for (int off = 1; off < 32; off <<= 1) csum += __shfl_xor(csum, off);
  const int c = c0 + tr;
  if ((c & 31) == L) p4[c >> 5] += 1.0f;      // P' = P + I (residual folded in)
  unsigned short* Pp = Pbf + (size_t)b * CC * CC + (size_t)c * CC;
#pragma unroll
  for (int j = 0; j < 4; ++j) Pp[L + 32 * j] = (unsigned short)bf16rne(p4[j]);
  if (L == 0) c0v[b * CC + c] = csum;
}

// ---------------------------------------------------------------------------
// K3 (MFMA): out[c][n] = sum_e P'[c][e]*x[e][n] + c0[c]  (identity in P').
// 256-n tile per block staged ONCE to LDS (transposed bf16, swizzled);
// P' fragments hoisted to registers per c-half and reused across 4 subtiles.
// Output via nontemporal stores. grid (64 n-tiles, 16 images), 4 waves.
// ---------------------------------------------------------------------------
__global__ __launch_bounds__(256, 2) void k3_mfma(const float* __restrict__ x,
    const unsigned short* __restrict__ Pbf, const float* __restrict__ c0v,
    float* __restrict__ out) {
  const int im = blockIdx.y;
  const int pb = im & 7;
  const int n0 = blockIdx.x * 256;
  const float* X = x + (size_t)im * NFULL;
  float* O = out + (size_t)im * NFULL;
  __shared__ unsigned short XT[256 * 128];   // swizzled: byte ^ (((n>>2)&15)<<4)
  __shared__ float c0l[128];
  const int t = threadIdx.x;
  if (t < 128) c0l[t] = c0v[pb * CC + t];
#pragma unroll
  for (int p = 0; p < 16; ++p) {
    int d0 = 2 * (t >> 4) + 32 * (p & 3);
    int n4 = (t & 15) * 4 + 64 * (p >> 2);
    f32x4 x0 = *(const f32x4*)(X + (size_t)d0 * NSP + n0 + n4);
    f32x4 x1 = *(const f32x4*)(X + (size_t)(d0 + 1) * NSP + n0 + n4);
#pragma unroll
    for (int i = 0; i < 4; ++i) {
      int n = n4 + i;
      __hip_bfloat162 h2 = __float22bfloat162_rn(make_float2(x0[i], x1[i]));
      unsigned pk = *reinterpret_cast<unsigned*>(&h2);
      int off = (n * 256 + d0 * 2) ^ (((n >> 2) & 15) << 4);
      *(unsigned*)((char*)XT + off) = pk;
    }
  }
  __syncthreads();

  const int w = t >> 6, l = t & 63;
  const int ln = l & 15, lg = l >> 4;
#pragma unroll
  for (int h = 0; h < 2; ++h) {
    const unsigned short* Pg = Pbf + (size_t)pb * (CC * CC)
                             + (size_t)(h * 64 + ln) * CC + lg * 8;
    s16x8 Af[4][4];
#pragma unroll
    for (int a = 0; a < 4; ++a)
#pragma unroll
      for (int kk = 0; kk < 4; ++kk)
        Af[a][kk] = *(const s16x8*)(Pg + a * 16 * CC + kk * 32);
#pragma unroll
    for (int sub = 0; sub < 4; ++sub) {
      int row = sub * 64 + w * 16 + ln;
      int sw = ((row >> 2) & 15) << 4;
      s16x8 bf[4];
#pragma unroll
      for (int kk = 0; kk < 4; ++kk)
        bf[kk] = *(const s16x8*)((char*)XT + ((row * 256 + kk * 64 + lg * 16) ^ sw));
      f32x4 acc[4];
#pragma unroll
      for (int a = 0; a < 4; ++a) acc[a] = (f32x4){0.f, 0.f, 0.f, 0.f};
#pragma unroll
      for (int kk = 0; kk < 4; ++kk)
#pragma unroll
        for (int a = 0; a < 4; ++a)
          acc[a] = __builtin_amdgcn_mfma_f32_16x16x32_bf16(Af[a][kk], bf[kk], acc[a], 0, 0, 0);
      int n = n0 + sub * 64 + w * 16 + ln;
#pragma unroll
      for (int a = 0; a < 4; ++a)
#pragma unroll
        for (int r = 0; r < 4; ++r) {
          int c = h * 64 + a * 16 + lg * 4 + r;
          __builtin_nontemporal_store(acc[a][r] + c0l[c], O + (size_t)c * NSP + n);
        }
    }
  }
}

// ---------------------------------------------------------------------------
extern "C" void kernel_launch(void* const* d_in, const int* in_sizes, int n_in,
                              void* d_out, int out_size, void* d_ws, size_t ws_size,
                              hipStream_t stream) {
  (void)in_sizes; (void)n_in; (void)out_size;
  const float* x  = (const float*)d_in[0];
  const float* qw = (const float*)d_in[1];
  const float* qb = (const float*)d_in[2];
  const float* kw = (const float*)d_in[3];
  const float* kb = (const float*)d_in[4];
  const float* vw = (const float*)d_in[5];
  const float* vb = (const float*)d_in[6];
  float* out = (float*)d_out;
  float* ws = (float*)d_ws;
  float* M   = ws;                       // 8*128*128  (M, rs, rt contiguous)
  float* rs  = M + 131072;               // 8*128
  float* rt  = rs + 1024;
  float* AST = rt + 1024;                // 8*128*128
  float* ATS = AST + 131072;
  unsigned short* Pbf = (unsigned short*)(ATS + 131072);  // 8*128*128 bf16
  float* c0v = ATS + 131072 + 65536;
  float* Mpart = c0v + 1024;
  const size_t base_floats = (size_t)(Mpart - ws);

  int NB, mode;
  if (ws_size >= (base_floats + (size_t)64 * (131072 + 2048)) * 4) { NB = 64; mode = 0; }
  else if (ws_size >= (base_floats + (size_t)32 * (131072 + 2048)) * 4) { NB = 32; mode = 0; }
  else { NB = 32; mode = 1; }
  const int nst = (16384 / NB) / 32;     // 32-n stages per chunk
  float* rtpart = Mpart + (size_t)NB * 131072;   // NB*8*128
  float* rspart = rtpart + (size_t)NB * 1024;    // NB*8*128

  if (mode == 1) zerok<<<(133120 + 255) / 256, 256, 0, stream>>>(M, 133120);
  k1_mfma<<<dim3(NB, 8), 256, 0, stream>>>(x, mode ? M : Mpart, rs, rt,
                                           rspart, rtpart, nst, mode);
  if (mode == 0)
    k1_reduce<<<130, 256, 0, stream>>>(Mpart, rspart, rtpart, M, rs, rt, NB);
  k2ab<<<dim3(16, 8), 256, 0, stream>>>(M, qw, kw, qb, kb, rs, rt, AST, ATS);
  k2cd<<<dim3(16, 8), 256, 0, stream>>>(AST, ATS, vw, vb, Pbf, c0v);
  k3_mfma<<<dim3(64, 16), 256, 0, stream>>>(x, Pbf, c0v, out);
}

// Round 13
// 143.764 us; speedup vs baseline: 1.1533x; 1.0241x over previous
//
#include <hip/hip_runtime.h>
#include <hip/hip_bf16.h>

#define CC 128
#define NSP 16384              // 128*128 spatial
#define NFULL (CC * NSP)

typedef float f32x4 __attribute__((ext_vector_type(4)));
typedef short s16x8 __attribute__((ext_vector_type(8)));
typedef unsigned int u32x4 __attribute__((ext_vector_type(4)));

#define GLOAD16(g, l) __builtin_amdgcn_global_load_lds( \
    (const __attribute__((address_space(1))) void*)(g), \
    (__attribute__((address_space(3))) void*)(l), 16, 0, 0)

__device__ __forceinline__ unsigned bf16rne(float f) {
  unsigned u = __float_as_uint(f);
  return ((u + 0x7FFFu + ((u >> 16) & 1u)) >> 16) & 0xFFFFu;
}

// RNE hi/lo split of a float pair -> packed {hi, lo} u32 (bf16x2 each)
__device__ __forceinline__ uint2 packpair(float x0, float x1) {
  __hip_bfloat162 h2 = __float22bfloat162_rn(make_float2(x0, x1));
  unsigned hu = *reinterpret_cast<unsigned*>(&h2);   // lo16=bf16(x0), hi16=bf16(x1)
  float hf0 = __uint_as_float(hu << 16);
  float hf1 = __uint_as_float(hu & 0xFFFF0000u);
  __hip_bfloat162 l2 = __float22bfloat162_rn(make_float2(x0 - hf0, x1 - hf1));
  unsigned lu = *reinterpret_cast<unsigned*>(&l2);
  return make_uint2(hu, lu);
}

// zero M/rs/rt (mode-1 fallback only)
__global__ __launch_bounds__(256) void zerok(float* __restrict__ p, int n) {
  int i = blockIdx.x * 256 + threadIdx.x;
  if (i < n) p[i] = 0.f;
}

// ---------------------------------------------------------------------------
// K1 (MFMA, global_load_lds staged): per (chunk,b): partial Xt*Xs^T over
// 32-n stages. Raw f32 tiles DMA'd to LDS (16B gload_lds, no VGPR trip),
// double-buffered; next stage issued before MFMA so the barrier drain is
// covered. bf16 hi/lo conversion at fragment-read time.
// ---------------------------------------------------------------------------
__global__ __launch_bounds__(256, 2) void k1_mfma(const float* __restrict__ x,
    float* __restrict__ Mdst, float* __restrict__ rs, float* __restrict__ rt,
    float* __restrict__ rspart, float* __restrict__ rtpart,
    int nst, int mode) {
  const int b = blockIdx.y;
  const int chunk = blockIdx.x;
  const int n0 = chunk * (nst * 32);
  const int t = threadIdx.x;
  const int w = t >> 6, l = t & 63;
  const int wr = w >> 1, wc = w & 1;
  const int lr = l & 15, lg = l >> 4;
  __shared__ __align__(16) char LB[2][2][128 * 128];  // [dbuf][A/B][row*128B] = 64KB
  const float* Xs = x + (size_t)b * NFULL;
  const float* Xt = x + (size_t)(b + 8) * NFULL;
  const int srow0 = w * 32 + (l >> 3);     // staging row base for this lane
  const int sn16x = (l & 7);               // slot index before swizzle

  f32x4 acc[4][4];
#pragma unroll
  for (int a = 0; a < 4; ++a)
#pragma unroll
    for (int bb = 0; bb < 4; ++bb) acc[a][bb] = (f32x4){0.f, 0.f, 0.f, 0.f};
  float rtp[4] = {0.f, 0.f, 0.f, 0.f};
  float rsp[4] = {0.f, 0.f, 0.f, 0.f};

  // prologue: issue stage 0 into buf 0
  {
#pragma unroll
    for (int i = 0; i < 4; ++i) {
      int row = srow0 + i * 8;
      int n16 = sn16x ^ (row & 7);
      GLOAD16(Xt + (size_t)row * NSP + n0 + n16 * 4, &LB[0][0][(w * 32 + i * 8) * 128]);
      GLOAD16(Xs + (size_t)row * NSP + n0 + n16 * 4, &LB[0][1][(w * 32 + i * 8) * 128]);
    }
  }

  for (int s = 0; s < nst; ++s) {
    const int cur = s & 1;
    __syncthreads();                 // vmcnt drain: buf[cur] complete; prev reads done
    if (s + 1 < nst) {               // issue next stage into other buffer (hides under MFMA)
      const int nb = n0 + (s + 1) * 32;
#pragma unroll
      for (int i = 0; i < 4; ++i) {
        int row = srow0 + i * 8;
        int n16 = sn16x ^ (row & 7);
        GLOAD16(Xt + (size_t)row * NSP + nb + n16 * 4, &LB[cur ^ 1][0][(w * 32 + i * 8) * 128]);
        GLOAD16(Xs + (size_t)row * NSP + nb + n16 * 4, &LB[cur ^ 1][1][(w * 32 + i * 8) * 128]);
      }
    }
    const char* A = &LB[cur][0][0];
    const char* B = &LB[cur][1][0];
    s16x8 ah[4], al[4], bh[4], bl[4];
#pragma unroll
    for (int a = 0; a < 4; ++a) {
      int row = wr * 64 + a * 16 + lr;
      int base = row * 128, sw = row & 7;
      f32x4 f0 = *(const f32x4*)(A + base + (((lg * 2) ^ sw) << 4));
      f32x4 f1 = *(const f32x4*)(A + base + (((lg * 2 + 1) ^ sw) << 4));
      rtp[a] += ((f0[0] + f0[1]) + (f0[2] + f0[3])) + ((f1[0] + f1[1]) + (f1[2] + f1[3]));
      uint2 p0 = packpair(f0[0], f0[1]);
      uint2 p1 = packpair(f0[2], f0[3]);
      uint2 p2 = packpair(f1[0], f1[1]);
      uint2 p3 = packpair(f1[2], f1[3]);
      u32x4 H = {p0.x, p1.x, p2.x, p3.x};
      u32x4 L = {p0.y, p1.y, p2.y, p3.y};
      ah[a] = __builtin_bit_cast(s16x8, H);
      al[a] = __builtin_bit_cast(s16x8, L);
    }
#pragma unroll
    for (int bb = 0; bb < 4; ++bb) {
      int row = wc * 64 + bb * 16 + lr;
      int base = row * 128, sw = row & 7;
      f32x4 f0 = *(const f32x4*)(B + base + (((lg * 2) ^ sw) << 4));
      f32x4 f1 = *(const f32x4*)(B + base + (((lg * 2 + 1) ^ sw) << 4));
      rsp[bb] += ((f0[0] + f0[1]) + (f0[2] + f0[3])) + ((f1[0] + f1[1]) + (f1[2] + f1[3]));
      uint2 p0 = packpair(f0[0], f0[1]);
      uint2 p1 = packpair(f0[2], f0[3]);
      uint2 p2 = packpair(f1[0], f1[1]);
      uint2 p3 = packpair(f1[2], f1[3]);
      u32x4 H = {p0.x, p1.x, p2.x, p3.x};
      u32x4 L = {p0.y, p1.y, p2.y, p3.y};
      bh[bb] = __builtin_bit_cast(s16x8, H);
      bl[bb] = __builtin_bit_cast(s16x8, L);
    }
#pragma unroll
    for (int a = 0; a < 4; ++a)
#pragma unroll
      for (int bb = 0; bb < 4; ++bb) {
        acc[a][bb] = __builtin_amdgcn_mfma_f32_16x16x32_bf16(ah[a], bh[bb], acc[a][bb], 0, 0, 0);
        acc[a][bb] = __builtin_amdgcn_mfma_f32_16x16x32_bf16(ah[a], bl[bb], acc[a][bb], 0, 0, 0);
        acc[a][bb] = __builtin_amdgcn_mfma_f32_16x16x32_bf16(al[a], bh[bb], acc[a][bb], 0, 0, 0);
      }
  }

  // row sums: reduce over lg (k-groups) via lanes l^16, l^32.
#pragma unroll
  for (int a = 0; a < 4; ++a) {
    float vt = rtp[a];
    vt += __shfl_xor(vt, 16);
    vt += __shfl_xor(vt, 32);
    float vs = rsp[a];
    vs += __shfl_xor(vs, 16);
    vs += __shfl_xor(vs, 32);
    if (l < 16) {
      if (wc == 0) {
        int row = wr * 64 + a * 16 + l;
        if (mode == 0) rtpart[((size_t)chunk * 8 + b) * CC + row] = vt;
        else atomicAdd(&rt[b * CC + row], vt);
      }
      if (wr == 0) {
        int row = wc * 64 + a * 16 + l;
        if (mode == 0) rspart[((size_t)chunk * 8 + b) * CC + row] = vs;
        else atomicAdd(&rs[b * CC + row], vs);
      }
    }
  }

  const int rquad = lg << 2;
  if (mode == 0) {
    float* Mp = Mdst + ((size_t)chunk * 8 + b) * (CC * CC);
#pragma unroll
    for (int a = 0; a < 4; ++a)
#pragma unroll
      for (int bb = 0; bb < 4; ++bb)
#pragma unroll
        for (int r = 0; r < 4; ++r) {
          int i = wr * 64 + a * 16 + rquad + r;
          int j = wc * 64 + bb * 16 + lr;
          Mp[i * CC + j] = acc[a][bb][r];
        }
  } else {
    float* Mp = Mdst + (size_t)b * (CC * CC);
#pragma unroll
    for (int a = 0; a < 4; ++a)
#pragma unroll
      for (int bb = 0; bb < 4; ++bb)
#pragma unroll
        for (int r = 0; r < 4; ++r) {
          int i = wr * 64 + a * 16 + rquad + r;
          int j = wc * 64 + bb * 16 + lr;
          atomicAdd(&Mp[i * CC + j], acc[a][bb][r]);
        }
  }
}

// Sum partials, vectorized. Blocks [0,128): M. Block 128: rt. Block 129: rs.
__global__ __launch_bounds__(256) void k1_reduce(const float* __restrict__ Mpart,
    const float* __restrict__ rspart, const float* __restrict__ rtpart,
    float* __restrict__ M, float* __restrict__ rs, float* __restrict__ rt,
    int NB) {
  const int t = threadIdx.x;
  if (blockIdx.x < 128) {
    const int i4 = blockIdx.x * 256 + t;     // < 32768
    const int b = i4 >> 12;
    const int e = (i4 & 4095) * 4;
    f32x4 s = (f32x4){0.f, 0.f, 0.f, 0.f};
    for (int c = 0; c < NB; ++c) {
      f32x4 v = *(const f32x4*)(Mpart + ((size_t)c * 8 + b) * (CC * CC) + e);
      s += v;
    }
    *(f32x4*)(M + (size_t)b * CC * CC + e) = s;
  } else if (blockIdx.x == 128) {
    const int e = t * 4;                      // < 1024
    f32x4 s = (f32x4){0.f, 0.f, 0.f, 0.f};
    for (int c = 0; c < NB; ++c) s += *(const f32x4*)(rtpart + (size_t)c * 1024 + e);
    *(f32x4*)(rt + e) = s;
  } else {
    const int e = t * 4;
    f32x4 s = (f32x4){0.f, 0.f, 0.f, 0.f};
    for (int c = 0; c < NB; ++c) s += *(const f32x4*)(rspart + (size_t)c * 1024 + e);
    *(f32x4*)(rs + e) = s;
  }
}

// ---------------------------------------------------------------------------
// K2ab fused: T1=Wq*M, T2=Wq*M^T, us/ut, G + softmax (st & ts).
// grid (16 c-groups of 8 rows, 8 b). Cols strided: lane L owns {L+32j}.
// ---------------------------------------------------------------------------
__global__ __launch_bounds__(256) void k2ab(const float* __restrict__ M,
    const float* __restrict__ qw, const float* __restrict__ kw,
    const float* __restrict__ qb, const float* __restrict__ kb,
    const float* __restrict__ rs, const float* __restrict__ rt,
    float* __restrict__ Ast, float* __restrict__ Ats) {
  const int b = blockIdx.y;
  const int c0 = blockIdx.x * 8;
  __shared__ float Big[128][132];      // M, later Wk (132: 16B-aligned rows)
  __shared__ float Wq[8][128];
  __shared__ float T12[2][8][128];
  __shared__ float uvv[2][8];
  __shared__ float wv2[2][128];
  const int t = threadIdx.x;
  const float* Mb = M + (size_t)b * CC * CC;
#pragma unroll
  for (int p = 0; p < 16; ++p) {
    int f = p * 256 + t;
    int row = f >> 5, c4 = (f & 31) * 4;
    *(f32x4*)&Big[row][c4] = *(const f32x4*)(Mb + row * CC + c4);
  }
  { int row = t >> 5, c4 = (t & 31) * 4;
    *(f32x4*)&Wq[row][c4] = *(const f32x4*)(qw + (c0 + row) * CC + c4); }
  __syncthreads();
  if (t < 16) {
    int c = t & 7;
    const float* r = ((t < 8) ? rs : rt) + b * CC;
    float s = 0.f;
    for (int i = 0; i < CC; ++i) s += Wq[c][i] * r[i];
    uvv[(t < 8) ? 1 : 0][c] = s;       // us->[1], ut->[0]
  }
  const int tr = t >> 5;               // row 0..7
  const int L = t & 31;                // col lane
  {
    float a1[4] = {0.f, 0.f, 0.f, 0.f}, a2[4] = {0.f, 0.f, 0.f, 0.f};
    for (int i = 0; i < CC; ++i) {
      float wq = Wq[tr][i];
#pragma unroll
      for (int j = 0; j < 4; ++j) a1[j] += wq * Big[i][L + 32 * j];
    }
    for (int i4 = 0; i4 < 32; ++i4) {
      f32x4 wq4 = *(const f32x4*)&Wq[tr][i4 * 4];
#pragma unroll
      for (int j = 0; j < 4; ++j) {
        f32x4 m4 = *(const f32x4*)&Big[L + 32 * j][i4 * 4];
        a2[j] += wq4[0]*m4[0] + wq4[1]*m4[1] + wq4[2]*m4[2] + wq4[3]*m4[3];
      }
    }
#pragma unroll
    for (int j = 0; j < 4; ++j) {
      T12[0][tr][L + 32 * j] = a1[j];
      T12[1][tr][L + 32 * j] = a2[j];
    }
  }
  __syncthreads();
  // overwrite Big with Wk
#pragma unroll
  for (int p = 0; p < 16; ++p) {
    int f = p * 256 + t;
    int row = f >> 5, c4 = (f & 31) * 4;
    *(f32x4*)&Big[row][c4] = *(const f32x4*)(kw + row * CC + c4);
  }
  __syncthreads();
  {
    int d = t & 127, wh = t >> 7;      // 0: rs, 1: rt
    const float* r = (wh ? rt : rs) + b * CC;
    float s = 0.f;
    for (int i4 = 0; i4 < 32; ++i4) {
      f32x4 w4 = *(const f32x4*)&Big[d][i4 * 4];
      s += w4[0]*r[i4*4] + w4[1]*r[i4*4+1] + w4[2]*r[i4*4+2] + w4[3]*r[i4*4+3];
    }
    wv2[wh][d] = s;
  }
  __syncthreads();
  const int c = c0 + tr;
  const float bqc = qb[c];
#pragma unroll 1
  for (int which = 0; which < 2; ++which) {
    float g[4];
#pragma unroll
    for (int j = 0; j < 4; ++j) {
      int d = L + 32 * j;
      g[j] = uvv[which][tr] * kb[d] + bqc * wv2[which][d] + 16384.f * bqc * kb[d];
    }
    for (int j4 = 0; j4 < 32; ++j4) {
      f32x4 tv4 = *(const f32x4*)&T12[which][tr][j4 * 4];
#pragma unroll
      for (int j = 0; j < 4; ++j) {
        f32x4 w4 = *(const f32x4*)&Big[L + 32 * j][j4 * 4];
        g[j] += tv4[0]*w4[0] + tv4[1]*w4[1] + tv4[2]*w4[2] + tv4[3]*w4[3];
      }
    }
    float m = fmaxf(fmaxf(g[0], g[1]), fmaxf(g[2], g[3]));
#pragma unroll
    for (int off = 1; off < 32; off <<= 1) m = fmaxf(m, __shfl_xor(m, off));
    float s = 0.f;
#pragma unroll
    for (int j = 0; j < 4; ++j) { g[j] = expf(g[j] - m); s += g[j]; }
#pragma unroll
    for (int off = 1; off < 32; off <<= 1) s += __shfl_xor(s, off);
    const float inv = 1.f / s;
    float* A = (which ? Ats : Ast) + (size_t)b * CC * CC + (size_t)c * CC;
#pragma unroll
    for (int j = 0; j < 4; ++j) A[L + 32 * j] = g[j] * inv;
  }
}

// ---------------------------------------------------------------------------
// K2cd fused: L = Ast*Ats^T, softmax -> Att, P' = Att*Wv + I (bf16), c0.
// grid (16 c-groups of 8 rows, 8 b).
// ---------------------------------------------------------------------------
__global__ __launch_bounds__(256) void k2cd(const float* __restrict__ Ast,
    const float* __restrict__ Ats, const float* __restrict__ vw,
    const float* __restrict__ vb, unsigned short* __restrict__ Pbf,
    float* __restrict__ c0v) {
  const int b = blockIdx.y;
  const int c0 = blockIdx.x * 8;
  __shared__ float Big[128][132];      // Ats, later Wv[d][i]
  __shared__ float Tl[8][128];
  __shared__ float Al[8][128];
  const int t = threadIdx.x;
  const float* Bb = Ats + (size_t)b * CC * CC;
  const float* Tb = Ast + (size_t)b * CC * CC;
#pragma unroll
  for (int p = 0; p < 16; ++p) {
    int f = p * 256 + t;
    int row = f >> 5, c4 = (f & 31) * 4;
    *(f32x4*)&Big[row][c4] = *(const f32x4*)(Bb + row * CC + c4);
  }
  { int row = t >> 5, c4 = (t & 31) * 4;
    *(f32x4*)&Tl[row][c4] = *(const f32x4*)(Tb + (c0 + row) * CC + c4); }
  __syncthreads();
  const int tr = t >> 5;
  const int L = t & 31;
  {
    float g[4] = {0.f, 0.f, 0.f, 0.f};
    for (int e4 = 0; e4 < 32; ++e4) {
      f32x4 tv4 = *(const f32x4*)&Tl[tr][e4 * 4];
#pragma unroll
      for (int j = 0; j < 4; ++j) {
        f32x4 a4 = *(const f32x4*)&Big[L + 32 * j][e4 * 4];
        g[j] += tv4[0]*a4[0] + tv4[1]*a4[1] + tv4[2]*a4[2] + tv4[3]*a4[3];
      }
    }
    float m = fmaxf(fmaxf(g[0], g[1]), fmaxf(g[2], g[3]));
#pragma unroll
    for (int off = 1; off < 32; off <<= 1) m = fmaxf(m, __shfl_xor(m, off));
    float s = 0.f;
#pragma unroll
    for (int j = 0; j < 4; ++j) { g[j] = expf(g[j] - m); s += g[j]; }
#pragma unroll
    for (int off = 1; off < 32; off <<= 1) s += __shfl_xor(s, off);
    const float inv = 1.f / s;
#pragma unroll
    for (int j = 0; j < 4; ++j) Al[tr][L + 32 * j] = g[j] * inv;
  }
  __syncthreads();
  // overwrite Big with Wv[d][i]
#pragma unroll
  for (int p = 0; p < 16; ++p) {
    int f = p * 256 + t;
    int row = f >> 5, c4 = (f & 31) * 4;
    *(f32x4*)&Big[row][c4] = *(const f32x4*)(vw + row * CC + c4);
  }
  __syncthreads();
  float p4[4] = {0.f, 0.f, 0.f, 0.f};
  for (int d = 0; d < CC; ++d) {
    float av = Al[tr][d];
#pragma unroll
    for (int j = 0; j < 4; ++j) p4[j] += av * Big[d][L + 32 * j];
  }
  float csum = 0.f;
#pragma unroll
  for (int j = 0; j < 4; ++j) csum += Al[tr][L + 32 * j] * vb[L + 32 * j];
#pragma unroll
  for (int off = 1; off < 32; off <<= 1) csum += __shfl_xor(csum, off);
  const int c = c0 + tr;
  if ((c & 31) == L) p4[c >> 5] += 1.0f;      // P' = P + I (residual folded in)
  unsigned short* Pp = Pbf + (size_t)b * CC * CC + (size_t)c * CC;
#pragma unroll
  for (int j = 0; j < 4; ++j) Pp[L + 32 * j] = (unsigned short)bf16rne(p4[j]);
  if (L == 0) c0v[b * CC + c] = csum;
}

// ---------------------------------------------------------------------------
// K3 (MFMA): out[c][n] = sum_e P'[c][e]*x[e][n] + c0[c]  (identity in P').
// 256-n tile staged ONCE to LDS (transposed bf16). NEW uniform swizzle
// g(n) = ((n&3)<<1)^((n>>2)&7): conflict-free on BOTH u32 writes (2-way)
// and b128 reads (8 lanes/slot-group = ideal; old layout was 2x-serialized).
// h=0 P' fragments prefetched ABOVE the staging barrier (hides 16 L2 loads).
// NT output stores. grid (64 n-tiles, 16 images), 4 waves.
// ---------------------------------------------------------------------------
__global__ __launch_bounds__(256, 2) void k3_mfma(const float* __restrict__ x,
    const unsigned short* __restrict__ Pbf, const float* __restrict__ c0v,
    float* __restrict__ out) {
  const int im = blockIdx.y;
  const int pb = im & 7;
  const int n0 = blockIdx.x * 256;
  const float* X = x + (size_t)im * NFULL;
  float* O = out + (size_t)im * NFULL;
  __shared__ unsigned short XT[256 * 128];
  __shared__ float c0l[128];
  const int t = threadIdx.x;
  const int w = t >> 6, l = t & 63;
  const int ln = l & 15, lg = l >> 4;
  if (t < 128) c0l[t] = c0v[pb * CC + t];
#pragma unroll
  for (int p = 0; p < 16; ++p) {
    int d0 = 2 * (t >> 4) + 32 * (p & 3);
    int n4 = (t & 15) * 4 + 64 * (p >> 2);
    f32x4 x0 = *(const f32x4*)(X + (size_t)d0 * NSP + n0 + n4);
    f32x4 x1 = *(const f32x4*)(X + (size_t)(d0 + 1) * NSP + n0 + n4);
#pragma unroll
    for (int i = 0; i < 4; ++i) {
      int n = n4 + i;
      __hip_bfloat162 h2 = __float22bfloat162_rn(make_float2(x0[i], x1[i]));
      unsigned pk = *reinterpret_cast<unsigned*>(&h2);
      int g = ((((n & 3) << 1) ^ ((n >> 2) & 7)) << 4);
      int off = (n * 256 + d0 * 2) ^ g;
      *(unsigned*)((char*)XT + off) = pk;
    }
  }
  // prefetch h=0 P' fragments BEFORE the barrier (independent global loads)
  const unsigned short* Pg0 = Pbf + (size_t)pb * (CC * CC) + (size_t)ln * CC + lg * 8;
  s16x8 Af0[4][4];
#pragma unroll
  for (int a = 0; a < 4; ++a)
#pragma unroll
    for (int kk = 0; kk < 4; ++kk)
      Af0[a][kk] = *(const s16x8*)(Pg0 + a * 16 * CC + kk * 32);
  __syncthreads();

#pragma unroll
  for (int h = 0; h < 2; ++h) {
    s16x8 Af[4][4];
    if (h == 0) {
#pragma unroll
      for (int a = 0; a < 4; ++a)
#pragma unroll
        for (int kk = 0; kk < 4; ++kk) Af[a][kk] = Af0[a][kk];
    } else {
      const unsigned short* Pg = Pg0 + (size_t)64 * CC;
#pragma unroll
      for (int a = 0; a < 4; ++a)
#pragma unroll
        for (int kk = 0; kk < 4; ++kk)
          Af[a][kk] = *(const s16x8*)(Pg + a * 16 * CC + kk * 32);
    }
#pragma unroll
    for (int sub = 0; sub < 4; ++sub) {
      int row = sub * 64 + w * 16 + ln;
      int g = ((((row & 3) << 1) ^ ((row >> 2) & 7)) << 4);
      s16x8 bf[4];
#pragma unroll
      for (int kk = 0; kk < 4; ++kk)
        bf[kk] = *(const s16x8*)((char*)XT + ((row * 256 + kk * 64 + lg * 16) ^ g));
      f32x4 acc[4];
#pragma unroll
      for (int a = 0; a < 4; ++a) acc[a] = (f32x4){0.f, 0.f, 0.f, 0.f};
#pragma unroll
      for (int kk = 0; kk < 4; ++kk)
#pragma unroll
        for (int a = 0; a < 4; ++a)
          acc[a] = __builtin_amdgcn_mfma_f32_16x16x32_bf16(Af[a][kk], bf[kk], acc[a], 0, 0, 0);
      int n = n0 + sub * 64 + w * 16 + ln;
#pragma unroll
      for (int a = 0; a < 4; ++a)
#pragma unroll
        for (int r = 0; r < 4; ++r) {
          int c = h * 64 + a * 16 + lg * 4 + r;
          __builtin_nontemporal_store(acc[a][r] + c0l[c], O + (size_t)c * NSP + n);
        }
    }
  }
}

// ---------------------------------------------------------------------------
extern "C" void kernel_launch(void* const* d_in, const int* in_sizes, int n_in,
                              void* d_out, int out_size, void* d_ws, size_t ws_size,
                              hipStream_t stream) {
  (void)in_sizes; (void)n_in; (void)out_size;
  const float* x  = (const float*)d_in[0];
  const float* qw = (const float*)d_in[1];
  const float* qb = (const float*)d_in[2];
  const float* kw = (const float*)d_in[3];
  const float* kb = (const float*)d_in[4];
  const float* vw = (const float*)d_in[5];
  const float* vb = (const float*)d_in[6];
  float* out = (float*)d_out;
  float* ws = (float*)d_ws;
  float* M   = ws;                       // 8*128*128  (M, rs, rt contiguous)
  float* rs  = M + 131072;               // 8*128
  float* rt  = rs + 1024;
  float* AST = rt + 1024;                // 8*128*128
  float* ATS = AST + 131072;
  unsigned short* Pbf = (unsigned short*)(ATS + 131072);  // 8*128*128 bf16
  float* c0v = ATS + 131072 + 65536;
  float* Mpart = c0v + 1024;
  const size_t base_floats = (size_t)(Mpart - ws);

  int NB, mode;
  if (ws_size >= (base_floats + (size_t)64 * (131072 + 2048)) * 4) { NB = 64; mode = 0; }
  else if (ws_size >= (base_floats + (size_t)32 * (131072 + 2048)) * 4) { NB = 32; mode = 0; }
  else { NB = 32; mode = 1; }
  const int nst = (16384 / NB) / 32;     // 32-n stages per chunk
  float* rtpart = Mpart + (size_t)NB * 131072;   // NB*8*128
  float* rspart = rtpart + (size_t)NB * 1024;    // NB*8*128

  if (mode == 1) zerok<<<(133120 + 255) / 256, 256, 0, stream>>>(M, 133120);
  k1_mfma<<<dim3(NB, 8), 256, 0, stream>>>(x, mode ? M : Mpart, rs, rt,
                                           rspart, rtpart, nst, mode);
  if (mode == 0)
    k1_reduce<<<130, 256, 0, stream>>>(Mpart, rspart, rtpart, M, rs, rt, NB);
  k2ab<<<dim3(16, 8), 256, 0, stream>>>(M, qw, kw, qb, kb, rs, rt, AST, ATS);
  k2cd<<<dim3(16, 8), 256, 0, stream>>>(AST, ATS, vw, vb, Pbf, c0v);
  k3_mfma<<<dim3(64, 16), 256, 0, stream>>>(x, Pbf, c0v, out);
}

// Round 14
// 137.226 us; speedup vs baseline: 1.2083x; 1.0476x over previous
//
#include <hip/hip_runtime.h>
#include <hip/hip_bf16.h>

#define CC 128
#define NSP 16384              // 128*128 spatial
#define NFULL (CC * NSP)

typedef float f32x4 __attribute__((ext_vector_type(4)));
typedef short s16x8 __attribute__((ext_vector_type(8)));
typedef unsigned int u32x4 __attribute__((ext_vector_type(4)));

#define GLOAD16(g, l) __builtin_amdgcn_global_load_lds( \
    (const __attribute__((address_space(1))) void*)(g), \
    (__attribute__((address_space(3))) void*)(l), 16, 0, 0)

__device__ __forceinline__ unsigned bf16rne(float f) {
  unsigned u = __float_as_uint(f);
  return ((u + 0x7FFFu + ((u >> 16) & 1u)) >> 16) & 0xFFFFu;
}

// RNE hi/lo split of a float pair -> packed {hi, lo} u32 (bf16x2 each)
__device__ __forceinline__ uint2 packpair(float x0, float x1) {
  __hip_bfloat162 h2 = __float22bfloat162_rn(make_float2(x0, x1));
  unsigned hu = *reinterpret_cast<unsigned*>(&h2);   // lo16=bf16(x0), hi16=bf16(x1)
  float hf0 = __uint_as_float(hu << 16);
  float hf1 = __uint_as_float(hu & 0xFFFF0000u);
  __hip_bfloat162 l2 = __float22bfloat162_rn(make_float2(x0 - hf0, x1 - hf1));
  unsigned lu = *reinterpret_cast<unsigned*>(&l2);
  return make_uint2(hu, lu);
}

// zero M/rs/rt (mode-1 fallback only)
__global__ __launch_bounds__(256) void zerok(float* __restrict__ p, int n) {
  int i = blockIdx.x * 256 + threadIdx.x;
  if (i < n) p[i] = 0.f;
}

// ---------------------------------------------------------------------------
// K1 (MFMA, global_load_lds staged): per (chunk,b): partial Xt*Xs^T over
// 32-n stages. Raw f32 tiles DMA'd to LDS (16B gload_lds, no VGPR trip),
// double-buffered; next stage issued before MFMA so the barrier drain is
// covered. bf16 hi/lo conversion at fragment-read time.
// NB=32 (R14): halves Mpart round-trip traffic vs NB=64 + keeps L3 for x.
// ---------------------------------------------------------------------------
__global__ __launch_bounds__(256, 2) void k1_mfma(const float* __restrict__ x,
    float* __restrict__ Mdst, float* __restrict__ rs, float* __restrict__ rt,
    float* __restrict__ rspart, float* __restrict__ rtpart,
    int nst, int mode) {
  const int b = blockIdx.y;
  const int chunk = blockIdx.x;
  const int n0 = chunk * (nst * 32);
  const int t = threadIdx.x;
  const int w = t >> 6, l = t & 63;
  const int wr = w >> 1, wc = w & 1;
  const int lr = l & 15, lg = l >> 4;
  __shared__ __align__(16) char LB[2][2][128 * 128];  // [dbuf][A/B][row*128B] = 64KB
  const float* Xs = x + (size_t)b * NFULL;
  const float* Xt = x + (size_t)(b + 8) * NFULL;
  const int srow0 = w * 32 + (l >> 3);     // staging row base for this lane
  const int sn16x = (l & 7);               // slot index before swizzle

  f32x4 acc[4][4];
#pragma unroll
  for (int a = 0; a < 4; ++a)
#pragma unroll
    for (int bb = 0; bb < 4; ++bb) acc[a][bb] = (f32x4){0.f, 0.f, 0.f, 0.f};
  float rtp[4] = {0.f, 0.f, 0.f, 0.f};
  float rsp[4] = {0.f, 0.f, 0.f, 0.f};

  // prologue: issue stage 0 into buf 0
  {
#pragma unroll
    for (int i = 0; i < 4; ++i) {
      int row = srow0 + i * 8;
      int n16 = sn16x ^ (row & 7);
      GLOAD16(Xt + (size_t)row * NSP + n0 + n16 * 4, &LB[0][0][(w * 32 + i * 8) * 128]);
      GLOAD16(Xs + (size_t)row * NSP + n0 + n16 * 4, &LB[0][1][(w * 32 + i * 8) * 128]);
    }
  }

  for (int s = 0; s < nst; ++s) {
    const int cur = s & 1;
    __syncthreads();                 // vmcnt drain: buf[cur] complete; prev reads done
    if (s + 1 < nst) {               // issue next stage into other buffer (hides under MFMA)
      const int nb = n0 + (s + 1) * 32;
#pragma unroll
      for (int i = 0; i < 4; ++i) {
        int row = srow0 + i * 8;
        int n16 = sn16x ^ (row & 7);
        GLOAD16(Xt + (size_t)row * NSP + nb + n16 * 4, &LB[cur ^ 1][0][(w * 32 + i * 8) * 128]);
        GLOAD16(Xs + (size_t)row * NSP + nb + n16 * 4, &LB[cur ^ 1][1][(w * 32 + i * 8) * 128]);
      }
    }
    const char* A = &LB[cur][0][0];
    const char* B = &LB[cur][1][0];
    s16x8 ah[4], al[4], bh[4], bl[4];
#pragma unroll
    for (int a = 0; a < 4; ++a) {
      int row = wr * 64 + a * 16 + lr;
      int base = row * 128, sw = row & 7;
      f32x4 f0 = *(const f32x4*)(A + base + (((lg * 2) ^ sw) << 4));
      f32x4 f1 = *(const f32x4*)(A + base + (((lg * 2 + 1) ^ sw) << 4));
      rtp[a] += ((f0[0] + f0[1]) + (f0[2] + f0[3])) + ((f1[0] + f1[1]) + (f1[2] + f1[3]));
      uint2 p0 = packpair(f0[0], f0[1]);
      uint2 p1 = packpair(f0[2], f0[3]);
      uint2 p2 = packpair(f1[0], f1[1]);
      uint2 p3 = packpair(f1[2], f1[3]);
      u32x4 H = {p0.x, p1.x, p2.x, p3.x};
      u32x4 L = {p0.y, p1.y, p2.y, p3.y};
      ah[a] = __builtin_bit_cast(s16x8, H);
      al[a] = __builtin_bit_cast(s16x8, L);
    }
#pragma unroll
    for (int bb = 0; bb < 4; ++bb) {
      int row = wc * 64 + bb * 16 + lr;
      int base = row * 128, sw = row & 7;
      f32x4 f0 = *(const f32x4*)(B + base + (((lg * 2) ^ sw) << 4));
      f32x4 f1 = *(const f32x4*)(B + base + (((lg * 2 + 1) ^ sw) << 4));
      rsp[bb] += ((f0[0] + f0[1]) + (f0[2] + f0[3])) + ((f1[0] + f1[1]) + (f1[2] + f1[3]));
      uint2 p0 = packpair(f0[0], f0[1]);
      uint2 p1 = packpair(f0[2], f0[3]);
      uint2 p2 = packpair(f1[0], f1[1]);
      uint2 p3 = packpair(f1[2], f1[3]);
      u32x4 H = {p0.x, p1.x, p2.x, p3.x};
      u32x4 L = {p0.y, p1.y, p2.y, p3.y};
      bh[bb] = __builtin_bit_cast(s16x8, H);
      bl[bb] = __builtin_bit_cast(s16x8, L);
    }
#pragma unroll
    for (int a = 0; a < 4; ++a)
#pragma unroll
      for (int bb = 0; bb < 4; ++bb) {
        acc[a][bb] = __builtin_amdgcn_mfma_f32_16x16x32_bf16(ah[a], bh[bb], acc[a][bb], 0, 0, 0);
        acc[a][bb] = __builtin_amdgcn_mfma_f32_16x16x32_bf16(ah[a], bl[bb], acc[a][bb], 0, 0, 0);
        acc[a][bb] = __builtin_amdgcn_mfma_f32_16x16x32_bf16(al[a], bh[bb], acc[a][bb], 0, 0, 0);
      }
  }

  // row sums: reduce over lg (k-groups) via lanes l^16, l^32.
#pragma unroll
  for (int a = 0; a < 4; ++a) {
    float vt = rtp[a];
    vt += __shfl_xor(vt, 16);
    vt += __shfl_xor(vt, 32);
    float vs = rsp[a];
    vs += __shfl_xor(vs, 16);
    vs += __shfl_xor(vs, 32);
    if (l < 16) {
      if (wc == 0) {
        int row = wr * 64 + a * 16 + l;
        if (mode == 0) rtpart[((size_t)chunk * 8 + b) * CC + row] = vt;
        else atomicAdd(&rt[b * CC + row], vt);
      }
      if (wr == 0) {
        int row = wc * 64 + a * 16 + l;
        if (mode == 0) rspart[((size_t)chunk * 8 + b) * CC + row] = vs;
        else atomicAdd(&rs[b * CC + row], vs);
      }
    }
  }

  const int rquad = lg << 2;
  if (mode == 0) {
    float* Mp = Mdst + ((size_t)chunk * 8 + b) * (CC * CC);
#pragma unroll
    for (int a = 0; a < 4; ++a)
#pragma unroll
      for (int bb = 0; bb < 4; ++bb)
#pragma unroll
        for (int r = 0; r < 4; ++r) {
          int i = wr * 64 + a * 16 + rquad + r;
          int j = wc * 64 + bb * 16 + lr;
          Mp[i * CC + j] = acc[a][bb][r];
        }
  } else {
    float* Mp = Mdst + (size_t)b * (CC * CC);
#pragma unroll
    for (int a = 0; a < 4; ++a)
#pragma unroll
      for (int bb = 0; bb < 4; ++bb)
#pragma unroll
        for (int r = 0; r < 4; ++r) {
          int i = wr * 64 + a * 16 + rquad + r;
          int j = wc * 64 + bb * 16 + lr;
          atomicAdd(&Mp[i * CC + j], acc[a][bb][r]);
        }
  }
}

// Sum partials, vectorized. Blocks [0,128): M. Block 128: rt. Block 129: rs.
__global__ __launch_bounds__(256) void k1_reduce(const float* __restrict__ Mpart,
    const float* __restrict__ rspart, const float* __restrict__ rtpart,
    float* __restrict__ M, float* __restrict__ rs, float* __restrict__ rt,
    int NB) {
  const int t = threadIdx.x;
  if (blockIdx.x < 128) {
    const int i4 = blockIdx.x * 256 + t;     // < 32768
    const int b = i4 >> 12;
    const int e = (i4 & 4095) * 4;
    f32x4 s = (f32x4){0.f, 0.f, 0.f, 0.f};
    for (int c = 0; c < NB; ++c) {
      f32x4 v = *(const f32x4*)(Mpart + ((size_t)c * 8 + b) * (CC * CC) + e);
      s += v;
    }
    *(f32x4*)(M + (size_t)b * CC * CC + e) = s;
  } else if (blockIdx.x == 128) {
    const int e = t * 4;                      // < 1024
    f32x4 s = (f32x4){0.f, 0.f, 0.f, 0.f};
    for (int c = 0; c < NB; ++c) s += *(const f32x4*)(rtpart + (size_t)c * 1024 + e);
    *(f32x4*)(rt + e) = s;
  } else {
    const int e = t * 4;
    f32x4 s = (f32x4){0.f, 0.f, 0.f, 0.f};
    for (int c = 0; c < NB; ++c) s += *(const f32x4*)(rspart + (size_t)c * 1024 + e);
    *(f32x4*)(rs + e) = s;
  }
}

// ---------------------------------------------------------------------------
// K2ab fused: T1=Wq*M, T2=Wq*M^T, us/ut, G + softmax (st & ts).
// grid (16 c-groups of 8 rows, 8 b). Cols strided: lane L owns {L+32j}.
// ---------------------------------------------------------------------------
__global__ __launch_bounds__(256) void k2ab(const float* __restrict__ M,
    const float* __restrict__ qw, const float* __restrict__ kw,
    const float* __restrict__ qb, const float* __restrict__ kb,
    const float* __restrict__ rs, const float* __restrict__ rt,
    float* __restrict__ Ast, float* __restrict__ Ats) {
  const int b = blockIdx.y;
  const int c0 = blockIdx.x * 8;
  __shared__ float Big[128][132];      // M, later Wk (132: 16B-aligned rows)
  __shared__ float Wq[8][128];
  __shared__ float T12[2][8][128];
  __shared__ float uvv[2][8];
  __shared__ float wv2[2][128];
  const int t = threadIdx.x;
  const float* Mb = M + (size_t)b * CC * CC;
#pragma unroll
  for (int p = 0; p < 16; ++p) {
    int f = p * 256 + t;
    int row = f >> 5, c4 = (f & 31) * 4;
    *(f32x4*)&Big[row][c4] = *(const f32x4*)(Mb + row * CC + c4);
  }
  { int row = t >> 5, c4 = (t & 31) * 4;
    *(f32x4*)&Wq[row][c4] = *(const f32x4*)(qw + (c0 + row) * CC + c4); }
  __syncthreads();
  if (t < 16) {
    int c = t & 7;
    const float* r = ((t < 8) ? rs : rt) + b * CC;
    float s = 0.f;
    for (int i = 0; i < CC; ++i) s += Wq[c][i] * r[i];
    uvv[(t < 8) ? 1 : 0][c] = s;       // us->[1], ut->[0]
  }
  const int tr = t >> 5;               // row 0..7
  const int L = t & 31;                // col lane
  {
    float a1[4] = {0.f, 0.f, 0.f, 0.f}, a2[4] = {0.f, 0.f, 0.f, 0.f};
    for (int i = 0; i < CC; ++i) {
      float wq = Wq[tr][i];
#pragma unroll
      for (int j = 0; j < 4; ++j) a1[j] += wq * Big[i][L + 32 * j];
    }
    for (int i4 = 0; i4 < 32; ++i4) {
      f32x4 wq4 = *(const f32x4*)&Wq[tr][i4 * 4];
#pragma unroll
      for (int j = 0; j < 4; ++j) {
        f32x4 m4 = *(const f32x4*)&Big[L + 32 * j][i4 * 4];
        a2[j] += wq4[0]*m4[0] + wq4[1]*m4[1] + wq4[2]*m4[2] + wq4[3]*m4[3];
      }
    }
#pragma unroll
    for (int j = 0; j < 4; ++j) {
      T12[0][tr][L + 32 * j] = a1[j];
      T12[1][tr][L + 32 * j] = a2[j];
    }
  }
  __syncthreads();
  // overwrite Big with Wk
#pragma unroll
  for (int p = 0; p < 16; ++p) {
    int f = p * 256 + t;
    int row = f >> 5, c4 = (f & 31) * 4;
    *(f32x4*)&Big[row][c4] = *(const f32x4*)(kw + row * CC + c4);
  }
  __syncthreads();
  {
    int d = t & 127, wh = t >> 7;      // 0: rs, 1: rt
    const float* r = (wh ? rt : rs) + b * CC;
    float s = 0.f;
    for (int i4 = 0; i4 < 32; ++i4) {
      f32x4 w4 = *(const f32x4*)&Big[d][i4 * 4];
      s += w4[0]*r[i4*4] + w4[1]*r[i4*4+1] + w4[2]*r[i4*4+2] + w4[3]*r[i4*4+3];
    }
    wv2[wh][d] = s;
  }
  __syncthreads();
  const int c = c0 + tr;
  const float bqc = qb[c];
#pragma unroll 1
  for (int which = 0; which < 2; ++which) {
    float g[4];
#pragma unroll
    for (int j = 0; j < 4; ++j) {
      int d = L + 32 * j;
      g[j] = uvv[which][tr] * kb[d] + bqc * wv2[which][d] + 16384.f * bqc * kb[d];
    }
    for (int j4 = 0; j4 < 32; ++j4) {
      f32x4 tv4 = *(const f32x4*)&T12[which][tr][j4 * 4];
#pragma unroll
      for (int j = 0; j < 4; ++j) {
        f32x4 w4 = *(const f32x4*)&Big[L + 32 * j][j4 * 4];
        g[j] += tv4[0]*w4[0] + tv4[1]*w4[1] + tv4[2]*w4[2] + tv4[3]*w4[3];
      }
    }
    float m = fmaxf(fmaxf(g[0], g[1]), fmaxf(g[2], g[3]));
#pragma unroll
    for (int off = 1; off < 32; off <<= 1) m = fmaxf(m, __shfl_xor(m, off));
    float s = 0.f;
#pragma unroll
    for (int j = 0; j < 4; ++j) { g[j] = expf(g[j] - m); s += g[j]; }
#pragma unroll
    for (int off = 1; off < 32; off <<= 1) s += __shfl_xor(s, off);
    const float inv = 1.f / s;
    float* A = (which ? Ats : Ast) + (size_t)b * CC * CC + (size_t)c * CC;
#pragma unroll
    for (int j = 0; j < 4; ++j) A[L + 32 * j] = g[j] * inv;
  }
}

// ---------------------------------------------------------------------------
// K2cd fused: L = Ast*Ats^T, softmax -> Att, P' = Att*Wv + I (bf16), c0.
// grid (16 c-groups of 8 rows, 8 b).
// ---------------------------------------------------------------------------
__global__ __launch_bounds__(256) void k2cd(const float* __restrict__ Ast,
    const float* __restrict__ Ats, const float* __restrict__ vw,
    const float* __restrict__ vb, unsigned short* __restrict__ Pbf,
    float* __restrict__ c0v) {
  const int b = blockIdx.y;
  const int c0 = blockIdx.x * 8;
  __shared__ float Big[128][132];      // Ats, later Wv[d][i]
  __shared__ float Tl[8][128];
  __shared__ float Al[8][128];
  const int t = threadIdx.x;
  const float* Bb = Ats + (size_t)b * CC * CC;
  const float* Tb = Ast + (size_t)b * CC * CC;
#pragma unroll
  for (int p = 0; p < 16; ++p) {
    int f = p * 256 + t;
    int row = f >> 5, c4 = (f & 31) * 4;
    *(f32x4*)&Big[row][c4] = *(const f32x4*)(Bb + row * CC + c4);
  }
  { int row = t >> 5, c4 = (t & 31) * 4;
    *(f32x4*)&Tl[row][c4] = *(const f32x4*)(Tb + (c0 + row) * CC + c4); }
  __syncthreads();
  const int tr = t >> 5;
  const int L = t & 31;
  {
    float g[4] = {0.f, 0.f, 0.f, 0.f};
    for (int e4 = 0; e4 < 32; ++e4) {
      f32x4 tv4 = *(const f32x4*)&Tl[tr][e4 * 4];
#pragma unroll
      for (int j = 0; j < 4; ++j) {
        f32x4 a4 = *(const f32x4*)&Big[L + 32 * j][e4 * 4];
        g[j] += tv4[0]*a4[0] + tv4[1]*a4[1] + tv4[2]*a4[2] + tv4[3]*a4[3];
      }
    }
    float m = fmaxf(fmaxf(g[0], g[1]), fmaxf(g[2], g[3]));
#pragma unroll
    for (int off = 1; off < 32; off <<= 1) m = fmaxf(m, __shfl_xor(m, off));
    float s = 0.f;
#pragma unroll
    for (int j = 0; j < 4; ++j) { g[j] = expf(g[j] - m); s += g[j]; }
#pragma unroll
    for (int off = 1; off < 32; off <<= 1) s += __shfl_xor(s, off);
    const float inv = 1.f / s;
#pragma unroll
    for (int j = 0; j < 4; ++j) Al[tr][L + 32 * j] = g[j] * inv;
  }
  __syncthreads();
  // overwrite Big with Wv[d][i]
#pragma unroll
  for (int p = 0; p < 16; ++p) {
    int f = p * 256 + t;
    int row = f >> 5, c4 = (f & 31) * 4;
    *(f32x4*)&Big[row][c4] = *(const f32x4*)(vw + row * CC + c4);
  }
  __syncthreads();
  float p4[4] = {0.f, 0.f, 0.f, 0.f};
  for (int d = 0; d < CC; ++d) {
    float av = Al[tr][d];
#pragma unroll
    for (int j = 0; j < 4; ++j) p4[j] += av * Big[d][L + 32 * j];
  }
  float csum = 0.f;
#pragma unroll
  for (int j = 0; j < 4; ++j) csum += Al[tr][L + 32 * j] * vb[L + 32 * j];
#pragma unroll
  for (int off = 1; off < 32; off <<= 1) csum += __shfl_xor(csum, off);
  const int c = c0 + tr;
  if ((c & 31) == L) p4[c >> 5] += 1.0f;      // P' = P + I (residual folded in)
  unsigned short* Pp = Pbf + (size_t)b * CC * CC + (size_t)c * CC;
#pragma unroll
  for (int j = 0; j < 4; ++j) Pp[L + 32 * j] = (unsigned short)bf16rne(p4[j]);
  if (L == 0) c0v[b * CC + c] = csum;
}

// ---------------------------------------------------------------------------
// K3 (MFMA): out[c][n] = sum_e P'[c][e]*x[e][n] + c0[c]  (identity in P').
// 256-n tile staged ONCE to LDS (transposed bf16). Uniform swizzle
// g(n) = ((n&3)<<1)^((n>>2)&7): conflict-free on writes AND b128 reads.
// h=0 P' fragments prefetched above the staging barrier. NT output stores.
// grid (64 n-tiles, 16 images), 4 waves.
// ---------------------------------------------------------------------------
__global__ __launch_bounds__(256, 2) void k3_mfma(const float* __restrict__ x,
    const unsigned short* __restrict__ Pbf, const float* __restrict__ c0v,
    float* __restrict__ out) {
  const int im = blockIdx.y;
  const int pb = im & 7;
  const int n0 = blockIdx.x * 256;
  const float* X = x + (size_t)im * NFULL;
  float* O = out + (size_t)im * NFULL;
  __shared__ unsigned short XT[256 * 128];
  __shared__ float c0l[128];
  const int t = threadIdx.x;
  const int w = t >> 6, l = t & 63;
  const int ln = l & 15, lg = l >> 4;
  if (t < 128) c0l[t] = c0v[pb * CC + t];
#pragma unroll
  for (int p = 0; p < 16; ++p) {
    int d0 = 2 * (t >> 4) + 32 * (p & 3);
    int n4 = (t & 15) * 4 + 64 * (p >> 2);
    f32x4 x0 = *(const f32x4*)(X + (size_t)d0 * NSP + n0 + n4);
    f32x4 x1 = *(const f32x4*)(X + (size_t)(d0 + 1) * NSP + n0 + n4);
#pragma unroll
    for (int i = 0; i < 4; ++i) {
      int n = n4 + i;
      __hip_bfloat162 h2 = __float22bfloat162_rn(make_float2(x0[i], x1[i]));
      unsigned pk = *reinterpret_cast<unsigned*>(&h2);
      int g = ((((n & 3) << 1) ^ ((n >> 2) & 7)) << 4);
      int off = (n * 256 + d0 * 2) ^ g;
      *(unsigned*)((char*)XT + off) = pk;
    }
  }
  // prefetch h=0 P' fragments BEFORE the barrier (independent global loads)
  const unsigned short* Pg0 = Pbf + (size_t)pb * (CC * CC) + (size_t)ln * CC + lg * 8;
  s16x8 Af0[4][4];
#pragma unroll
  for (int a = 0; a < 4; ++a)
#pragma unroll
    for (int kk = 0; kk < 4; ++kk)
      Af0[a][kk] = *(const s16x8*)(Pg0 + a * 16 * CC + kk * 32);
  __syncthreads();

#pragma unroll
  for (int h = 0; h < 2; ++h) {
    s16x8 Af[4][4];
    if (h == 0) {
#pragma unroll
      for (int a = 0; a < 4; ++a)
#pragma unroll
        for (int kk = 0; kk < 4; ++kk) Af[a][kk] = Af0[a][kk];
    } else {
      const unsigned short* Pg = Pg0 + (size_t)64 * CC;
#pragma unroll
      for (int a = 0; a < 4; ++a)
#pragma unroll
        for (int kk = 0; kk < 4; ++kk)
          Af[a][kk] = *(const s16x8*)(Pg + a * 16 * CC + kk * 32);
    }
#pragma unroll
    for (int sub = 0; sub < 4; ++sub) {
      int row = sub * 64 + w * 16 + ln;
      int g = ((((row & 3) << 1) ^ ((row >> 2) & 7)) << 4);
      s16x8 bf[4];
#pragma unroll
      for (int kk = 0; kk < 4; ++kk)
        bf[kk] = *(const s16x8*)((char*)XT + ((row * 256 + kk * 64 + lg * 16) ^ g));
      f32x4 acc[4];
#pragma unroll
      for (int a = 0; a < 4; ++a) acc[a] = (f32x4){0.f, 0.f, 0.f, 0.f};
#pragma unroll
      for (int kk = 0; kk < 4; ++kk)
#pragma unroll
        for (int a = 0; a < 4; ++a)
          acc[a] = __builtin_amdgcn_mfma_f32_16x16x32_bf16(Af[a][kk], bf[kk], acc[a], 0, 0, 0);
      int n = n0 + sub * 64 + w * 16 + ln;
#pragma unroll
      for (int a = 0; a < 4; ++a)
#pragma unroll
        for (int r = 0; r < 4; ++r) {
          int c = h * 64 + a * 16 + lg * 4 + r;
          __builtin_nontemporal_store(acc[a][r] + c0l[c], O + (size_t)c * NSP + n);
        }
    }
  }
}

// ---------------------------------------------------------------------------
extern "C" void kernel_launch(void* const* d_in, const int* in_sizes, int n_in,
                              void* d_out, int out_size, void* d_ws, size_t ws_size,
                              hipStream_t stream) {
  (void)in_sizes; (void)n_in; (void)out_size;
  const float* x  = (const float*)d_in[0];
  const float* qw = (const float*)d_in[1];
  const float* qb = (const float*)d_in[2];
  const float* kw = (const float*)d_in[3];
  const float* kb = (const float*)d_in[4];
  const float* vw = (const float*)d_in[5];
  const float* vb = (const float*)d_in[6];
  float* out = (float*)d_out;
  float* ws = (float*)d_ws;
  float* M   = ws;                       // 8*128*128  (M, rs, rt contiguous)
  float* rs  = M + 131072;               // 8*128
  float* rt  = rs + 1024;
  float* AST = rt + 1024;                // 8*128*128
  float* ATS = AST + 131072;
  unsigned short* Pbf = (unsigned short*)(ATS + 131072);  // 8*128*128 bf16
  float* c0v = ATS + 131072 + 65536;
  float* Mpart = c0v + 1024;
  const size_t base_floats = (size_t)(Mpart - ws);

  int NB, mode;
  if (ws_size >= (base_floats + (size_t)32 * (131072 + 2048)) * 4) { NB = 32; mode = 0; }
  else { NB = 32; mode = 1; }
  const int nst = (16384 / NB) / 32;     // 32-n stages per chunk (NB=32 -> 16)
  float* rtpart = Mpart + (size_t)NB * 131072;   // NB*8*128
  float* rspart = rtpart + (size_t)NB * 1024;    // NB*8*128

  if (mode == 1) zerok<<<(133120 + 255) / 256, 256, 0, stream>>>(M, 133120);
  k1_mfma<<<dim3(NB, 8), 256, 0, stream>>>(x, mode ? M : Mpart, rs, rt,
                                           rspart, rtpart, nst, mode);
  if (mode == 0)
    k1_reduce<<<130, 256, 0, stream>>>(Mpart, rspart, rtpart, M, rs, rt, NB);
  k2ab<<<dim3(16, 8), 256, 0, stream>>>(M, qw, kw, qb, kb, rs, rt, AST, ATS);
  k2cd<<<dim3(16, 8), 256, 0, stream>>>(AST, ATS, vw, vb, Pbf, c0v);
  k3_mfma<<<dim3(64, 16), 256, 0, stream>>>(x, Pbf, c0v, out);
}

// Round 15
// 125.687 us; speedup vs baseline: 1.3192x; 1.0918x over previous
//
#include <hip/hip_runtime.h>
#include <hip/hip_bf16.h>

#define CC 128
#define NSP 16384              // 128*128 spatial
#define NFULL (CC * NSP)

typedef float f32x4 __attribute__((ext_vector_type(4)));
typedef short s16x8 __attribute__((ext_vector_type(8)));
typedef unsigned int u32x4 __attribute__((ext_vector_type(4)));

#define GLOAD16(g, l) __builtin_amdgcn_global_load_lds( \
    (const __attribute__((address_space(1))) void*)(g), \
    (__attribute__((address_space(3))) void*)(l), 16, 0, 0)

__device__ __forceinline__ unsigned bf16rne(float f) {
  unsigned u = __float_as_uint(f);
  return ((u + 0x7FFFu + ((u >> 16) & 1u)) >> 16) & 0xFFFFu;
}

// RNE hi/lo split of a float pair -> packed {hi, lo} u32 (bf16x2 each)
__device__ __forceinline__ uint2 packpair(float x0, float x1) {
  __hip_bfloat162 h2 = __float22bfloat162_rn(make_float2(x0, x1));
  unsigned hu = *reinterpret_cast<unsigned*>(&h2);   // lo16=bf16(x0), hi16=bf16(x1)
  float hf0 = __uint_as_float(hu << 16);
  float hf1 = __uint_as_float(hu & 0xFFFF0000u);
  __hip_bfloat162 l2 = __float22bfloat162_rn(make_float2(x0 - hf0, x1 - hf1));
  unsigned lu = *reinterpret_cast<unsigned*>(&l2);
  return make_uint2(hu, lu);
}

// zero M/rs/rt (mode-1 fallback only)
__global__ __launch_bounds__(256) void zerok(float* __restrict__ p, int n) {
  int i = blockIdx.x * 256 + threadIdx.x;
  if (i < n) p[i] = 0.f;
}

// ---------------------------------------------------------------------------
// K1 (MFMA, global_load_lds staged): unchanged from R14 best.
// ---------------------------------------------------------------------------
__global__ __launch_bounds__(256, 2) void k1_mfma(const float* __restrict__ x,
    float* __restrict__ Mdst, float* __restrict__ rs, float* __restrict__ rt,
    float* __restrict__ rspart, float* __restrict__ rtpart,
    int nst, int mode) {
  const int b = blockIdx.y;
  const int chunk = blockIdx.x;
  const int n0 = chunk * (nst * 32);
  const int t = threadIdx.x;
  const int w = t >> 6, l = t & 63;
  const int wr = w >> 1, wc = w & 1;
  const int lr = l & 15, lg = l >> 4;
  __shared__ __align__(16) char LB[2][2][128 * 128];  // [dbuf][A/B][row*128B] = 64KB
  const float* Xs = x + (size_t)b * NFULL;
  const float* Xt = x + (size_t)(b + 8) * NFULL;
  const int srow0 = w * 32 + (l >> 3);
  const int sn16x = (l & 7);

  f32x4 acc[4][4];
#pragma unroll
  for (int a = 0; a < 4; ++a)
#pragma unroll
    for (int bb = 0; bb < 4; ++bb) acc[a][bb] = (f32x4){0.f, 0.f, 0.f, 0.f};
  float rtp[4] = {0.f, 0.f, 0.f, 0.f};
  float rsp[4] = {0.f, 0.f, 0.f, 0.f};

  {
#pragma unroll
    for (int i = 0; i < 4; ++i) {
      int row = srow0 + i * 8;
      int n16 = sn16x ^ (row & 7);
      GLOAD16(Xt + (size_t)row * NSP + n0 + n16 * 4, &LB[0][0][(w * 32 + i * 8) * 128]);
      GLOAD16(Xs + (size_t)row * NSP + n0 + n16 * 4, &LB[0][1][(w * 32 + i * 8) * 128]);
    }
  }

  for (int s = 0; s < nst; ++s) {
    const int cur = s & 1;
    __syncthreads();
    if (s + 1 < nst) {
      const int nb = n0 + (s + 1) * 32;
#pragma unroll
      for (int i = 0; i < 4; ++i) {
        int row = srow0 + i * 8;
        int n16 = sn16x ^ (row & 7);
        GLOAD16(Xt + (size_t)row * NSP + nb + n16 * 4, &LB[cur ^ 1][0][(w * 32 + i * 8) * 128]);
        GLOAD16(Xs + (size_t)row * NSP + nb + n16 * 4, &LB[cur ^ 1][1][(w * 32 + i * 8) * 128]);
      }
    }
    const char* A = &LB[cur][0][0];
    const char* B = &LB[cur][1][0];
    s16x8 ah[4], al[4], bh[4], bl[4];
#pragma unroll
    for (int a = 0; a < 4; ++a) {
      int row = wr * 64 + a * 16 + lr;
      int base = row * 128, sw = row & 7;
      f32x4 f0 = *(const f32x4*)(A + base + (((lg * 2) ^ sw) << 4));
      f32x4 f1 = *(const f32x4*)(A + base + (((lg * 2 + 1) ^ sw) << 4));
      rtp[a] += ((f0[0] + f0[1]) + (f0[2] + f0[3])) + ((f1[0] + f1[1]) + (f1[2] + f1[3]));
      uint2 p0 = packpair(f0[0], f0[1]);
      uint2 p1 = packpair(f0[2], f0[3]);
      uint2 p2 = packpair(f1[0], f1[1]);
      uint2 p3 = packpair(f1[2], f1[3]);
      u32x4 H = {p0.x, p1.x, p2.x, p3.x};
      u32x4 L = {p0.y, p1.y, p2.y, p3.y};
      ah[a] = __builtin_bit_cast(s16x8, H);
      al[a] = __builtin_bit_cast(s16x8, L);
    }
#pragma unroll
    for (int bb = 0; bb < 4; ++bb) {
      int row = wc * 64 + bb * 16 + lr;
      int base = row * 128, sw = row & 7;
      f32x4 f0 = *(const f32x4*)(B + base + (((lg * 2) ^ sw) << 4));
      f32x4 f1 = *(const f32x4*)(B + base + (((lg * 2 + 1) ^ sw) << 4));
      rsp[bb] += ((f0[0] + f0[1]) + (f0[2] + f0[3])) + ((f1[0] + f1[1]) + (f1[2] + f1[3]));
      uint2 p0 = packpair(f0[0], f0[1]);
      uint2 p1 = packpair(f0[2], f0[3]);
      uint2 p2 = packpair(f1[0], f1[1]);
      uint2 p3 = packpair(f1[2], f1[3]);
      u32x4 H = {p0.x, p1.x, p2.x, p3.x};
      u32x4 L = {p0.y, p1.y, p2.y, p3.y};
      bh[bb] = __builtin_bit_cast(s16x8, H);
      bl[bb] = __builtin_bit_cast(s16x8, L);
    }
#pragma unroll
    for (int a = 0; a < 4; ++a)
#pragma unroll
      for (int bb = 0; bb < 4; ++bb) {
        acc[a][bb] = __builtin_amdgcn_mfma_f32_16x16x32_bf16(ah[a], bh[bb], acc[a][bb], 0, 0, 0);
        acc[a][bb] = __builtin_amdgcn_mfma_f32_16x16x32_bf16(ah[a], bl[bb], acc[a][bb], 0, 0, 0);
        acc[a][bb] = __builtin_amdgcn_mfma_f32_16x16x32_bf16(al[a], bh[bb], acc[a][bb], 0, 0, 0);
      }
  }

#pragma unroll
  for (int a = 0; a < 4; ++a) {
    float vt = rtp[a];
    vt += __shfl_xor(vt, 16);
    vt += __shfl_xor(vt, 32);
    float vs = rsp[a];
    vs += __shfl_xor(vs, 16);
    vs += __shfl_xor(vs, 32);
    if (l < 16) {
      if (wc == 0) {
        int row = wr * 64 + a * 16 + l;
        if (mode == 0) rtpart[((size_t)chunk * 8 + b) * CC + row] = vt;
        else atomicAdd(&rt[b * CC + row], vt);
      }
      if (wr == 0) {
        int row = wc * 64 + a * 16 + l;
        if (mode == 0) rspart[((size_t)chunk * 8 + b) * CC + row] = vs;
        else atomicAdd(&rs[b * CC + row], vs);
      }
    }
  }

  const int rquad = lg << 2;
  if (mode == 0) {
    float* Mp = Mdst + ((size_t)chunk * 8 + b) * (CC * CC);
#pragma unroll
    for (int a = 0; a < 4; ++a)
#pragma unroll
      for (int bb = 0; bb < 4; ++bb)
#pragma unroll
        for (int r = 0; r < 4; ++r) {
          int i = wr * 64 + a * 16 + rquad + r;
          int j = wc * 64 + bb * 16 + lr;
          Mp[i * CC + j] = acc[a][bb][r];
        }
  } else {
    float* Mp = Mdst + (size_t)b * (CC * CC);
#pragma unroll
    for (int a = 0; a < 4; ++a)
#pragma unroll
      for (int bb = 0; bb < 4; ++bb)
#pragma unroll
        for (int r = 0; r < 4; ++r) {
          int i = wr * 64 + a * 16 + rquad + r;
          int j = wc * 64 + bb * 16 + lr;
          atomicAdd(&Mp[i * CC + j], acc[a][bb][r]);
        }
  }
}

// Sum partials, vectorized. Blocks [0,128): M. Block 128: rt. Block 129: rs.
__global__ __launch_bounds__(256) void k1_reduce(const float* __restrict__ Mpart,
    const float* __restrict__ rspart, const float* __restrict__ rtpart,
    float* __restrict__ M, float* __restrict__ rs, float* __restrict__ rt,
    int NB) {
  const int t = threadIdx.x;
  if (blockIdx.x < 128) {
    const int i4 = blockIdx.x * 256 + t;
    const int b = i4 >> 12;
    const int e = (i4 & 4095) * 4;
    f32x4 s = (f32x4){0.f, 0.f, 0.f, 0.f};
    for (int c = 0; c < NB; ++c) {
      f32x4 v = *(const f32x4*)(Mpart + ((size_t)c * 8 + b) * (CC * CC) + e);
      s += v;
    }
    *(f32x4*)(M + (size_t)b * CC * CC + e) = s;
  } else if (blockIdx.x == 128) {
    const int e = t * 4;
    f32x4 s = (f32x4){0.f, 0.f, 0.f, 0.f};
    for (int c = 0; c < NB; ++c) s += *(const f32x4*)(rtpart + (size_t)c * 1024 + e);
    *(f32x4*)(rt + e) = s;
  } else {
    const int e = t * 4;
    f32x4 s = (f32x4){0.f, 0.f, 0.f, 0.f};
    for (int c = 0; c < NB; ++c) s += *(const f32x4*)(rspart + (size_t)c * 1024 + e);
    *(f32x4*)(rs + e) = s;
  }
}

// ---------------------------------------------------------------------------
// K2ab fused (regrid: 32 c-groups of 4 rows, 8 b -> 256 blocks, 1 wave/row).
// Lane L (0..63) owns cols {L, L+64}; softmax = full-wave shfl reduce.
// ---------------------------------------------------------------------------
__global__ __launch_bounds__(256) void k2ab(const float* __restrict__ M,
    const float* __restrict__ qw, const float* __restrict__ kw,
    const float* __restrict__ qb, const float* __restrict__ kb,
    const float* __restrict__ rs, const float* __restrict__ rt,
    float* __restrict__ Ast, float* __restrict__ Ats) {
  const int b = blockIdx.y;
  const int c0 = blockIdx.x * 4;
  __shared__ float Big[128][132];      // M, later Wk
  __shared__ float Wq[4][128];
  __shared__ float T12[2][4][128];
  __shared__ float uvv[2][4];
  __shared__ float wv2[2][128];
  const int t = threadIdx.x;
  const float* Mb = M + (size_t)b * CC * CC;
#pragma unroll
  for (int p = 0; p < 16; ++p) {
    int f = p * 256 + t;
    int row = f >> 5, c4 = (f & 31) * 4;
    *(f32x4*)&Big[row][c4] = *(const f32x4*)(Mb + row * CC + c4);
  }
  if (t < 128) {
    int row = t >> 5, c4 = (t & 31) * 4;
    *(f32x4*)&Wq[row][c4] = *(const f32x4*)(qw + (c0 + row) * CC + c4);
  }
  __syncthreads();
  if (t < 8) {
    int c = t & 3;
    const float* r = ((t < 4) ? rs : rt) + b * CC;
    float s = 0.f;
    for (int i = 0; i < CC; ++i) s += Wq[c][i] * r[i];
    uvv[(t < 4) ? 1 : 0][c] = s;       // us->[1], ut->[0]
  }
  const int tr = t >> 6;               // row 0..3 (= wave)
  const int L = t & 63;                // col lane; owns {L, L+64}
  {
    float a1[2] = {0.f, 0.f}, a2[2] = {0.f, 0.f};
    for (int i = 0; i < CC; ++i) {
      float wq = Wq[tr][i];
#pragma unroll
      for (int j = 0; j < 2; ++j) a1[j] += wq * Big[i][L + 64 * j];
    }
    for (int i4 = 0; i4 < 32; ++i4) {
      f32x4 wq4 = *(const f32x4*)&Wq[tr][i4 * 4];
#pragma unroll
      for (int j = 0; j < 2; ++j) {
        f32x4 m4 = *(const f32x4*)&Big[L + 64 * j][i4 * 4];
        a2[j] += wq4[0]*m4[0] + wq4[1]*m4[1] + wq4[2]*m4[2] + wq4[3]*m4[3];
      }
    }
#pragma unroll
    for (int j = 0; j < 2; ++j) {
      T12[0][tr][L + 64 * j] = a1[j];
      T12[1][tr][L + 64 * j] = a2[j];
    }
  }
  __syncthreads();
  // overwrite Big with Wk
#pragma unroll
  for (int p = 0; p < 16; ++p) {
    int f = p * 256 + t;
    int row = f >> 5, c4 = (f & 31) * 4;
    *(f32x4*)&Big[row][c4] = *(const f32x4*)(kw + row * CC + c4);
  }
  __syncthreads();
  {
    int d = t & 127, wh = t >> 7;      // 0: rs, 1: rt
    const float* r = (wh ? rt : rs) + b * CC;
    float s = 0.f;
    for (int i4 = 0; i4 < 32; ++i4) {
      f32x4 w4 = *(const f32x4*)&Big[d][i4 * 4];
      s += w4[0]*r[i4*4] + w4[1]*r[i4*4+1] + w4[2]*r[i4*4+2] + w4[3]*r[i4*4+3];
    }
    wv2[wh][d] = s;
  }
  __syncthreads();
  const int c = c0 + tr;
  const float bqc = qb[c];
#pragma unroll 1
  for (int which = 0; which < 2; ++which) {
    float g[2];
#pragma unroll
    for (int j = 0; j < 2; ++j) {
      int d = L + 64 * j;
      g[j] = uvv[which][tr] * kb[d] + bqc * wv2[which][d] + 16384.f * bqc * kb[d];
    }
    for (int j4 = 0; j4 < 32; ++j4) {
      f32x4 tv4 = *(const f32x4*)&T12[which][tr][j4 * 4];
#pragma unroll
      for (int j = 0; j < 2; ++j) {
        f32x4 w4 = *(const f32x4*)&Big[L + 64 * j][j4 * 4];
        g[j] += tv4[0]*w4[0] + tv4[1]*w4[1] + tv4[2]*w4[2] + tv4[3]*w4[3];
      }
    }
    float m = fmaxf(g[0], g[1]);
#pragma unroll
    for (int off = 1; off < 64; off <<= 1) m = fmaxf(m, __shfl_xor(m, off));
    float s = g[0] = expf(g[0] - m);
    s += (g[1] = expf(g[1] - m));
#pragma unroll
    for (int off = 1; off < 64; off <<= 1) s += __shfl_xor(s, off);
    const float inv = 1.f / s;
    float* A = (which ? Ats : Ast) + (size_t)b * CC * CC + (size_t)c * CC;
    A[L] = g[0] * inv;
    A[L + 64] = g[1] * inv;
  }
}

// ---------------------------------------------------------------------------
// K2cd fused (regrid: 32 c-groups of 4 rows, 8 b -> 256 blocks).
// ---------------------------------------------------------------------------
__global__ __launch_bounds__(256) void k2cd(const float* __restrict__ Ast,
    const float* __restrict__ Ats, const float* __restrict__ vw,
    const float* __restrict__ vb, unsigned short* __restrict__ Pbf,
    float* __restrict__ c0v) {
  const int b = blockIdx.y;
  const int c0 = blockIdx.x * 4;
  __shared__ float Big[128][132];      // Ats, later Wv[d][i]
  __shared__ float Tl[4][128];
  __shared__ float Al[4][128];
  const int t = threadIdx.x;
  const float* Bb = Ats + (size_t)b * CC * CC;
  const float* Tb = Ast + (size_t)b * CC * CC;
#pragma unroll
  for (int p = 0; p < 16; ++p) {
    int f = p * 256 + t;
    int row = f >> 5, c4 = (f & 31) * 4;
    *(f32x4*)&Big[row][c4] = *(const f32x4*)(Bb + row * CC + c4);
  }
  if (t < 128) {
    int row = t >> 5, c4 = (t & 31) * 4;
    *(f32x4*)&Tl[row][c4] = *(const f32x4*)(Tb + (c0 + row) * CC + c4);
  }
  __syncthreads();
  const int tr = t >> 6;
  const int L = t & 63;
  {
    float g[2] = {0.f, 0.f};
    for (int e4 = 0; e4 < 32; ++e4) {
      f32x4 tv4 = *(const f32x4*)&Tl[tr][e4 * 4];
#pragma unroll
      for (int j = 0; j < 2; ++j) {
        f32x4 a4 = *(const f32x4*)&Big[L + 64 * j][e4 * 4];
        g[j] += tv4[0]*a4[0] + tv4[1]*a4[1] + tv4[2]*a4[2] + tv4[3]*a4[3];
      }
    }
    float m = fmaxf(g[0], g[1]);
#pragma unroll
    for (int off = 1; off < 64; off <<= 1) m = fmaxf(m, __shfl_xor(m, off));
    float s = g[0] = expf(g[0] - m);
    s += (g[1] = expf(g[1] - m));
#pragma unroll
    for (int off = 1; off < 64; off <<= 1) s += __shfl_xor(s, off);
    const float inv = 1.f / s;
    Al[tr][L] = g[0] * inv;
    Al[tr][L + 64] = g[1] * inv;
  }
  __syncthreads();
  // overwrite Big with Wv[d][i]
#pragma unroll
  for (int p = 0; p < 16; ++p) {
    int f = p * 256 + t;
    int row = f >> 5, c4 = (f & 31) * 4;
    *(f32x4*)&Big[row][c4] = *(const f32x4*)(vw + row * CC + c4);
  }
  __syncthreads();
  float p2[2] = {0.f, 0.f};
  for (int d = 0; d < CC; ++d) {
    float av = Al[tr][d];
#pragma unroll
    for (int j = 0; j < 2; ++j) p2[j] += av * Big[d][L + 64 * j];
  }
  float csum = Al[tr][L] * vb[L] + Al[tr][L + 64] * vb[L + 64];
#pragma unroll
  for (int off = 1; off < 64; off <<= 1) csum += __shfl_xor(csum, off);
  const int c = c0 + tr;
  if ((c & 63) == L) p2[c >> 6] += 1.0f;      // P' = P + I
  unsigned short* Pp = Pbf + (size_t)b * CC * CC + (size_t)c * CC;
  Pp[L] = (unsigned short)bf16rne(p2[0]);
  Pp[L + 64] = (unsigned short)bf16rne(p2[1]);
  if (L == 0) c0v[b * CC + c] = csum;
}

// ---------------------------------------------------------------------------
// K3 (MFMA, swapped operands): D = mfma(XT_frag, P'_frag) -> lane holds
// (c = lane&15 of tile, 4 CONSECUTIVE n) -> f32x4 NT stores (4x fewer store
// instructions, full 64B segments). Same fragment data/reads as before.
// grid (64 n-tiles, 16 images), 4 waves.
// ---------------------------------------------------------------------------
__global__ __launch_bounds__(256, 2) void k3_mfma(const float* __restrict__ x,
    const unsigned short* __restrict__ Pbf, const float* __restrict__ c0v,
    float* __restrict__ out) {
  const int im = blockIdx.y;
  const int pb = im & 7;
  const int n0 = blockIdx.x * 256;
  const float* X = x + (size_t)im * NFULL;
  float* O = out + (size_t)im * NFULL;
  __shared__ unsigned short XT[256 * 128];
  __shared__ float c0l[128];
  const int t = threadIdx.x;
  const int w = t >> 6, l = t & 63;
  const int ln = l & 15, lg = l >> 4;
  if (t < 128) c0l[t] = c0v[pb * CC + t];
#pragma unroll
  for (int p = 0; p < 16; ++p) {
    int d0 = 2 * (t >> 4) + 32 * (p & 3);
    int n4 = (t & 15) * 4 + 64 * (p >> 2);
    f32x4 x0 = *(const f32x4*)(X + (size_t)d0 * NSP + n0 + n4);
    f32x4 x1 = *(const f32x4*)(X + (size_t)(d0 + 1) * NSP + n0 + n4);
#pragma unroll
    for (int i = 0; i < 4; ++i) {
      int n = n4 + i;
      __hip_bfloat162 h2 = __float22bfloat162_rn(make_float2(x0[i], x1[i]));
      unsigned pk = *reinterpret_cast<unsigned*>(&h2);
      int g = ((((n & 3) << 1) ^ ((n >> 2) & 7)) << 4);
      int off = (n * 256 + d0 * 2) ^ g;
      *(unsigned*)((char*)XT + off) = pk;
    }
  }
  // prefetch h=0 P' fragments BEFORE the barrier
  const unsigned short* Pg0 = Pbf + (size_t)pb * (CC * CC) + (size_t)ln * CC + lg * 8;
  s16x8 Af0[4][4];
#pragma unroll
  for (int a = 0; a < 4; ++a)
#pragma unroll
    for (int kk = 0; kk < 4; ++kk)
      Af0[a][kk] = *(const s16x8*)(Pg0 + a * 16 * CC + kk * 32);
  __syncthreads();

#pragma unroll
  for (int h = 0; h < 2; ++h) {
    s16x8 Af[4][4];
    if (h == 0) {
#pragma unroll
      for (int a = 0; a < 4; ++a)
#pragma unroll
        for (int kk = 0; kk < 4; ++kk) Af[a][kk] = Af0[a][kk];
    } else {
      const unsigned short* Pg = Pg0 + (size_t)64 * CC;
#pragma unroll
      for (int a = 0; a < 4; ++a)
#pragma unroll
        for (int kk = 0; kk < 4; ++kk)
          Af[a][kk] = *(const s16x8*)(Pg + a * 16 * CC + kk * 32);
    }
#pragma unroll
    for (int sub = 0; sub < 4; ++sub) {
      int row = sub * 64 + w * 16 + ln;
      int g = ((((row & 3) << 1) ^ ((row >> 2) & 7)) << 4);
      s16x8 bf[4];
#pragma unroll
      for (int kk = 0; kk < 4; ++kk)
        bf[kk] = *(const s16x8*)((char*)XT + ((row * 256 + kk * 64 + lg * 16) ^ g));
      f32x4 acc[4];
#pragma unroll
      for (int a = 0; a < 4; ++a) acc[a] = (f32x4){0.f, 0.f, 0.f, 0.f};
#pragma unroll
      for (int kk = 0; kk < 4; ++kk)
#pragma unroll
        for (int a = 0; a < 4; ++a)
          acc[a] = __builtin_amdgcn_mfma_f32_16x16x32_bf16(bf[kk], Af[a][kk], acc[a], 0, 0, 0);
      // D: col = c-within-tile = ln, row = n-within-16 = lg*4 + r (consecutive)
      int nbase = n0 + sub * 64 + w * 16 + lg * 4;
#pragma unroll
      for (int a = 0; a < 4; ++a) {
        int c = h * 64 + a * 16 + ln;
        float cc0 = c0l[c];
        f32x4 r = acc[a];
        r[0] += cc0; r[1] += cc0; r[2] += cc0; r[3] += cc0;
        __builtin_nontemporal_store(r, (f32x4*)(O + (size_t)c * NSP + nbase));
      }
    }
  }
}

// ---------------------------------------------------------------------------
extern "C" void kernel_launch(void* const* d_in, const int* in_sizes, int n_in,
                              void* d_out, int out_size, void* d_ws, size_t ws_size,
                              hipStream_t stream) {
  (void)in_sizes; (void)n_in; (void)out_size;
  const float* x  = (const float*)d_in[0];
  const float* qw = (const float*)d_in[1];
  const float* qb = (const float*)d_in[2];
  const float* kw = (const float*)d_in[3];
  const float* kb = (const float*)d_in[4];
  const float* vw = (const float*)d_in[5];
  const float* vb = (const float*)d_in[6];
  float* out = (float*)d_out;
  float* ws = (float*)d_ws;
  float* M   = ws;                       // 8*128*128  (M, rs, rt contiguous)
  float* rs  = M + 131072;               // 8*128
  float* rt  = rs + 1024;
  float* AST = rt + 1024;                // 8*128*128
  float* ATS = AST + 131072;
  unsigned short* Pbf = (unsigned short*)(ATS + 131072);  // 8*128*128 bf16
  float* c0v = ATS + 131072 + 65536;
  float* Mpart = c0v + 1024;
  const size_t base_floats = (size_t)(Mpart - ws);

  int NB, mode;
  if (ws_size >= (base_floats + (size_t)32 * (131072 + 2048)) * 4) { NB = 32; mode = 0; }
  else { NB = 32; mode = 1; }
  const int nst = (16384 / NB) / 32;     // 32-n stages per chunk (NB=32 -> 16)
  float* rtpart = Mpart + (size_t)NB * 131072;   // NB*8*128
  float* rspart = rtpart + (size_t)NB * 1024;    // NB*8*128

  if (mode == 1) zerok<<<(133120 + 255) / 256, 256, 0, stream>>>(M, 133120);
  k1_mfma<<<dim3(NB, 8), 256, 0, stream>>>(x, mode ? M : Mpart, rs, rt,
                                           rspart, rtpart, nst, mode);
  if (mode == 0)
    k1_reduce<<<130, 256, 0, stream>>>(Mpart, rspart, rtpart, M, rs, rt, NB);
  k2ab<<<dim3(32, 8), 256, 0, stream>>>(M, qw, kw, qb, kb, rs, rt, AST, ATS);
  k2cd<<<dim3(32, 8), 256, 0, stream>>>(AST, ATS, vw, vb, Pbf, c0v);
  k3_mfma<<<dim3(64, 16), 256, 0, stream>>>(x, Pbf, c0v, out);
}